// Round 1
// baseline (4596.049 us; speedup 1.0000x reference)
//
#include <hip/hip_runtime.h>

typedef unsigned short u16;
typedef unsigned int   u32;
typedef __attribute__((ext_vector_type(8))) short s16x8;
typedef __attribute__((ext_vector_type(4))) float f32x4;

#define DEV static __device__ __forceinline__

constexpr int B_ = 512, T_ = 200, V_ = 99, H_ = 256;
constexpr int TV_ = T_ * V_;

// d_out f32 element offsets: (x_imp, y_out, y_score, x_loss, xus, xrs)
constexpr long long XIMP_O = 0;
constexpr long long YOUT_O = 10137600;
constexpr long long YSC_O  = 10138112;
constexpr long long LOSS_O = 10138624;
constexpr long long XUS_O  = 10138625;
constexpr long long XRS_O  = 20276225;

// workspace byte offsets
constexpr long long WS_MSUM  = 0;                               // 200 f32
constexpr long long WS_GAMMA = 1024;                            // [T][B][H] bf16
constexpr long long WS_XRPRE = WS_GAMMA + 2ll * T_ * B_ * H_;   // [T][B][V] bf16
constexpr long long WS_GIPRE = WS_XRPRE + 2ll * T_ * B_ * V_;   // [T][32][48][64][4] bf16 (C-frag layout)
constexpr long long WS_WTD   = WS_GIPRE + 2ll * T_ * 32 * 48 * 256;
constexpr long long WS_WU    = WS_WTD   + 64ll  * 1024;
constexpr long long WS_WV    = WS_WU    + 28ll  * 1024;
constexpr long long WS_WR    = WS_WV    + 28ll  * 1024;
constexpr long long WS_WHIST = WS_WR    + 28ll  * 1024;
constexpr long long WS_WIHX  = WS_WHIST + 56ll  * 1024;
constexpr long long WS_WIHM  = WS_WIHX  + 192ll * 1024;
constexpr long long WS_WHH   = WS_WIHM  + 192ll * 1024;
constexpr long long WS_LOSSP = WS_WHH   + 384ll * 1024;         // 32 f32

DEV u16 cvt_bf16(float f) {
  union { float f; u32 u; } v; v.f = f;
  u32 u = v.u;
  return (u16)((u + 0x7fffu + ((u >> 16) & 1u)) >> 16);
}
DEV float cvt_f32(u16 h) {
  union { u32 u; float f; } v; v.u = ((u32)h) << 16;
  return v.f;
}
DEV f32x4 mfma16(s16x8 a, s16x8 b, f32x4 c) {
  return __builtin_amdgcn_mfma_f32_16x16x32_bf16(a, b, c, 0, 0, 0);
}
// A-fragment from LDS row-major [16][stride] (u16 units): lane -> row=lane&15, k=(lane>>4)*8+j
DEV s16x8 ldsA(const u16* base, int stride, int lane, int kc) {
  return *reinterpret_cast<const s16x8*>(base + (lane & 15) * stride + kc * 32 + ((lane >> 4) << 3));
}
// B-fragment from packed global weights
DEV s16x8 ldB(const u16* w, int frag, int lane) {
  return *reinterpret_cast<const s16x8*>(w + ((long long)frag * 64 + lane) * 8);
}
DEV f32x4 unpack_bf4(const u16* p) {
  const u32* q = reinterpret_cast<const u32*>(p);
  u32 a = q[0], b = q[1];
  return (f32x4){cvt_f32((u16)(a & 0xffffu)), cvt_f32((u16)(a >> 16)),
                 cvt_f32((u16)(b & 0xffffu)), cvt_f32((u16)(b >> 16))};
}
DEV float sigm(float v) { return 1.f / (1.f + __expf(-v)); }
DEV float tanhx(float v) {
  float e = __expf(-2.f * fabsf(v));
  float t = (1.f - e) / (1.f + e);
  return v < 0.f ? -t : t;
}

// ---------------- K0: pack weights to bf16 MFMA-B fragment layout; zero msum ----------------
__global__ __launch_bounds__(256) void k0_pack(
    const float* __restrict__ W_td, const float* __restrict__ W_u, const float* __restrict__ W_v,
    const float* __restrict__ W_r, const float* __restrict__ W_hist, const float* __restrict__ W_ih,
    const float* __restrict__ W_hh, float* __restrict__ msum, u16* __restrict__ wsu) {
  if (blockIdx.x == 243) {
    if (threadIdx.x < T_) msum[threadIdx.x] = 0.f;
    return;
  }
  int frag = blockIdx.x * 4 + (threadIdx.x >> 6);
  int lane = threadIdx.x & 63;
  const float* src; long long off; int KC, koff, kmax, nmax, stride, diag = 0, f;
  if (frag < 64)       { f = frag;       src = W_td;   off = WS_WTD;   KC = 4; stride = 99;  koff = 0;  kmax = 99;  nmax = 256; }
  else if (frag < 92)  { f = frag - 64;  src = W_u;    off = WS_WU;    KC = 4; stride = 99;  koff = 0;  kmax = 99;  nmax = 99;  }
  else if (frag < 120) { f = frag - 92;  src = W_v;    off = WS_WV;    KC = 4; stride = 99;  koff = 0;  kmax = 99;  nmax = 99;  diag = 1; }
  else if (frag < 148) { f = frag - 120; src = W_r;    off = WS_WR;    KC = 4; stride = 99;  koff = 0;  kmax = 99;  nmax = 99;  diag = 1; }
  else if (frag < 204) { f = frag - 148; src = W_hist; off = WS_WHIST; KC = 8; stride = 256; koff = 0;  kmax = 256; nmax = 99;  }
  else if (frag < 396) { f = frag - 204; src = W_ih;   off = WS_WIHX;  KC = 4; stride = 198; koff = 0;  kmax = 99;  nmax = 768; }
  else if (frag < 588) { f = frag - 396; src = W_ih;   off = WS_WIHM;  KC = 4; stride = 198; koff = 99; kmax = 99;  nmax = 768; }
  else if (frag < 972) { f = frag - 588; src = W_hh;   off = WS_WHH;   KC = 8; stride = 256; koff = 0;  kmax = 256; nmax = 768; }
  else return;
  int nt = f / KC, kc = f % KC;
  int n = nt * 16 + (lane & 15);
  u16* dst = wsu + off / 2 + ((long long)f * 64 + lane) * 8;
#pragma unroll
  for (int j = 0; j < 8; j++) {
    int k = kc * 32 + ((lane >> 4) << 3) + j;
    float v = 0.f;
    if (k < kmax && n < nmax && !(diag && k == n)) v = src[(long long)n * stride + koff + k];
    dst[j] = cvt_bf16(v);
  }
}

// ---------------- K2: parallel precompute: gamma, xus(out), xr_pre, gi_pre, msum ----------------
__global__ __launch_bounds__(256) void k2_pre(
    const float* __restrict__ x, const float* __restrict__ xh, const float* __restrict__ uu,
    const float* __restrict__ m, const float* __restrict__ dd,
    const float* __restrict__ b_td, const float* __restrict__ b_u, const float* __restrict__ b_v,
    const float* __restrict__ b_r, const float* __restrict__ b_ih,
    float* __restrict__ msum, float* __restrict__ out, u16* __restrict__ wsu) {
  __shared__ __align__(16) u16 Abuf[4][16][136];
  const int tid = threadIdx.x, w = tid >> 6, lane = tid & 63;
  const int bc = blockIdx.x & 31, tg = blockIdx.x >> 5;
  const int b0 = bc * 16;
  const int cl = lane & 15, rq = (lane >> 4) << 2;
  const u16* wtd  = wsu + WS_WTD / 2;
  const u16* wu   = wsu + WS_WU / 2;
  const u16* wv   = wsu + WS_WV / 2;
  const u16* wr   = wsu + WS_WR / 2;
  const u16* wihx = wsu + WS_WIHX / 2;
  const u16* wihm = wsu + WS_WIHM / 2;
  u16* gam = wsu + WS_GAMMA / 2;
  u16* xrp = wsu + WS_XRPRE / 2;
  u16* gip = wsu + WS_GIPRE / 2;

  for (int it = 0; it < 4; it++) {
    const int t = tg * 16 + w * 4 + it;
    if (t >= T_) break;
    s16x8 fd[4], fu[4], fxb[4], fmx[4], fm[4];
    float mpart = 0.f;
#define STAGE(MODE, FR)                                                              \
    {                                                                                \
      for (int idx = lane; idx < 2048; idx += 64) {                                  \
        int row = idx >> 7, col = idx & 127; float v = 0.f;                          \
        if (col < V_) {                                                              \
          long long g = (long long)(b0 + row) * TV_ + (long long)t * V_ + col;       \
          if (MODE == 0) v = dd[g];                                                  \
          else if (MODE == 1) v = uu[g];                                             \
          else if (MODE == 2) { float mm = m[g]; v = mm * x[g] + (1.f - mm) * xh[g]; } \
          else if (MODE == 3) { v = m[g] * x[g]; }                                   \
          else { v = m[g]; mpart += v; }                                             \
        }                                                                            \
        Abuf[w][row][col] = cvt_bf16(v);                                             \
      }                                                                              \
      for (int kc = 0; kc < 4; kc++) FR[kc] = ldsA(&Abuf[w][0][0], 136, lane, kc);   \
    }
    STAGE(0, fd) STAGE(1, fu) STAGE(2, fxb) STAGE(3, fmx) STAGE(4, fm)
#undef STAGE
    float mp = mpart;
#pragma unroll
    for (int s = 32; s; s >>= 1) mp += __shfl_xor(mp, s);
    if (lane == 0) atomicAdd(&msum[t], mp);

    // V-wide GEMMs: unc / xu / xr_pre
    for (int nt = 0; nt < 7; nt++) {
      int col = nt * 16 + cl;
      float bu_ = 0.f, bv_ = 0.f, br_ = 0.f;
      if (col < V_) { bu_ = b_u[col]; bv_ = b_v[col]; br_ = b_r[col]; }
      f32x4 au = {bu_, bu_, bu_, bu_}, av = {bv_, bv_, bv_, bv_}, ar = {br_, br_, br_, br_};
#pragma unroll
      for (int kc = 0; kc < 4; kc++) {
        au = mfma16(fu[kc],  ldB(wu, nt * 4 + kc, lane), au);
        av = mfma16(fxb[kc], ldB(wv, nt * 4 + kc, lane), av);
        ar = mfma16(fmx[kc], ldB(wr, nt * 4 + kc, lane), ar);
      }
      if (col < V_) {
#pragma unroll
        for (int j = 0; j < 4; j++) {
          int b = b0 + rq + j;
          float unc = __expf(-fmaxf(au[j], 0.f));
          out[XUS_O + (long long)b * TV_ + (long long)t * V_ + col] = av[j] * unc;
          xrp[((long long)t * B_ + b) * V_ + col] = cvt_bf16(ar[j]);
        }
      }
    }
    // gi_pre (stored in C-fragment layout for the scan kernel)
    for (int nt = 0; nt < 48; nt++) {
      int col = nt * 16 + cl;
      float bi = b_ih[col];
      f32x4 a = {bi, bi, bi, bi};
#pragma unroll
      for (int kc = 0; kc < 4; kc++) {
        a = mfma16(fmx[kc], ldB(wihx, nt * 4 + kc, lane), a);
        a = mfma16(fm[kc],  ldB(wihm, nt * 4 + kc, lane), a);
      }
      u32 p0 = (u32)cvt_bf16(a[0]) | ((u32)cvt_bf16(a[1]) << 16);
      u32 p1 = (u32)cvt_bf16(a[2]) | ((u32)cvt_bf16(a[3]) << 16);
      u32* gp = reinterpret_cast<u32*>(gip + (((long long)t * 32 + bc) * 48 + nt) * 256 + (long long)lane * 4);
      gp[0] = p0; gp[1] = p1;
    }
    // gamma
    for (int nt = 0; nt < 16; nt++) {
      int col = nt * 16 + cl;
      float bt = b_td[col];
      f32x4 a = {bt, bt, bt, bt};
#pragma unroll
      for (int kc = 0; kc < 4; kc++) a = mfma16(fd[kc], ldB(wtd, nt * 4 + kc, lane), a);
#pragma unroll
      for (int j = 0; j < 4; j++) {
        int b = b0 + rq + j;
        gam[((long long)t * B_ + b) * H_ + col] = cvt_bf16(__expf(-fmaxf(a[j], 0.f)));
      }
    }
  }
}

// ---------------- K_SEQ: persistent recurrent scan; 32 WGs x 16 batch rows ----------------
__global__ __launch_bounds__(256, 1) void k_seq(
    const float* __restrict__ x, const float* __restrict__ m,
    const float* __restrict__ b_hist, const float* __restrict__ b_hh,
    const float* __restrict__ conv_w, const float* __restrict__ conv_b,
    const float* __restrict__ W_fc, const float* __restrict__ b_fc,
    const float* __restrict__ msum, float* out, u16* wsu) {
  __shared__ __align__(16) float h_s[16][264];
  __shared__ __align__(16) u16 hp_s[16][264];
  __shared__ __align__(16) u16 e_s[16][136];
  __shared__ __align__(16) u16 g_s[16][136];
  __shared__ float red_s[256];
  const int tid = threadIdx.x, w = tid >> 6, lane = tid & 63;
  const int cl = lane & 15, rq = (lane >> 4) << 2;
  const int b0 = blockIdx.x * 16;
  for (int i = tid; i < 16 * 264; i += 256) h_s[i / 264][i % 264] = 0.f;
  for (int i = tid; i < 16 * 136; i += 256) { e_s[i / 136][i % 136] = 0; g_s[i / 136][i % 136] = 0; }
  const float cw0 = conv_w[0], cw1 = conv_w[1], cb = conv_b[0];
  const u16* gam   = wsu + WS_GAMMA / 2;
  const u16* xrp   = wsu + WS_XRPRE / 2;
  const u16* gip   = wsu + WS_GIPRE / 2;
  const u16* whist = wsu + WS_WHIST / 2;
  const u16* wr    = wsu + WS_WR / 2;
  const u16* wihx  = wsu + WS_WIHX / 2;
  const u16* whh   = wsu + WS_WHH / 2;
  float loss_acc = 0.f;
  __syncthreads();

  for (int t = 0; t < T_; t++) {
    { // S1: hp = bf16(h * gamma_t)
      const int row = tid >> 4, c0 = (tid & 15) * 16;
      const u32* gp = reinterpret_cast<const u32*>(gam + ((long long)t * B_ + b0 + row) * H_ + c0);
      u32* hp32 = reinterpret_cast<u32*>(&hp_s[row][c0]);
      const float* hrow = &h_s[row][c0];
#pragma unroll
      for (int k = 0; k < 8; k++) {
        u32 gw = gp[k];
        u16 p0 = cvt_bf16(hrow[2 * k]     * cvt_f32((u16)(gw & 0xffffu)));
        u16 p1 = cvt_bf16(hrow[2 * k + 1] * cvt_f32((u16)(gw >> 16)));
        hp32[k] = (u32)p0 | ((u32)p1 << 16);
      }
    }
    __syncthreads();
    const float inv_ms = 1.f / (msum[t] + 1e-5f);
    s16x8 hf[8];
#pragma unroll
    for (int kc = 0; kc < 8; kc++) hf[kc] = ldsA(&hp_s[0][0], 264, lane, kc);

    // S2a: x_h tiles -> e = (1-m)*x_h
    float mreg[2][4] = {{0.f,0.f,0.f,0.f},{0.f,0.f,0.f,0.f}};
    float xreg[2][4] = {{0.f,0.f,0.f,0.f},{0.f,0.f,0.f,0.f}};
#pragma unroll
    for (int i = 0; i < 2; i++) {
      const int nt = w + 4 * i;
      if (nt < 7) {
        const int col = nt * 16 + cl;
        float bh = (col < V_) ? b_hist[col] : 0.f;
        f32x4 a = {bh, bh, bh, bh};
#pragma unroll
        for (int kc = 0; kc < 8; kc++) a = mfma16(hf[kc], ldB(whist, nt * 8 + kc, lane), a);
#pragma unroll
        for (int j = 0; j < 4; j++) {
          if (col < V_) {
            const int row = rq + j;
            long long g = (long long)(b0 + row) * TV_ + (long long)t * V_ + col;
            float mj = m[g], xj = x[g];
            mreg[i][j] = mj; xreg[i][j] = xj;
            e_s[row][col] = cvt_bf16((1.f - mj) * a[j]);
          }
        }
      }
    }
    __syncthreads();

    // S2b: xr, x_comb, loss, x_imp, xrs, g
    s16x8 ef[4];
#pragma unroll
    for (int kc = 0; kc < 4; kc++) ef[kc] = ldsA(&e_s[0][0], 136, lane, kc);
#pragma unroll
    for (int i = 0; i < 2; i++) {
      const int nt = w + 4 * i;
      if (nt < 7) {
        const int col = nt * 16 + cl;
        f32x4 a = {0.f, 0.f, 0.f, 0.f};
#pragma unroll
        for (int kc = 0; kc < 4; kc++) a = mfma16(ef[kc], ldB(wr, nt * 4 + kc, lane), a);
        if (col < V_) {
#pragma unroll
          for (int j = 0; j < 4; j++) {
            const int row = rq + j, b = b0 + row;
            long long g = (long long)b * TV_ + (long long)t * V_ + col;
            float xrv = a[j] + cvt_f32(xrp[((long long)t * B_ + b) * V_ + col]);
            float xuv = out[XUS_O + g];
            float xc = cw0 * xuv + cw1 * xrv + cb;
            loss_acc += fabsf(xreg[i][j] - xc) * mreg[i][j] * inv_ms;
            out[XIMP_O + g] = mreg[i][j] * xreg[i][j] + (1.f - mreg[i][j]) * xc;
            out[XRS_O + g] = xrv;
            g_s[row][col] = cvt_bf16((1.f - mreg[i][j]) * xc);
          }
        }
      }
    }
    __syncthreads();

    // S3/S4: gi = gi_pre + g@W_ihx^T ; gh = hp@W_hh^T ; GRU update
    s16x8 gf[4];
#pragma unroll
    for (int kc = 0; kc < 4; kc++) gf[kc] = ldsA(&g_s[0][0], 136, lane, kc);
#pragma unroll
    for (int ci = 0; ci < 4; ci++) {
      const int c = 4 * ci + w;
      const u16* gbase = gip + (((long long)t * 32 + blockIdx.x) * 48) * 256 + (long long)lane * 4;
      f32x4 gr = unpack_bf4(gbase + (long long)(c) * 256);
      f32x4 gz = unpack_bf4(gbase + (long long)(16 + c) * 256);
      f32x4 gn = unpack_bf4(gbase + (long long)(32 + c) * 256);
#pragma unroll
      for (int kc = 0; kc < 4; kc++) {
        gr = mfma16(gf[kc], ldB(wihx, (c)      * 4 + kc, lane), gr);
        gz = mfma16(gf[kc], ldB(wihx, (16 + c) * 4 + kc, lane), gz);
        gn = mfma16(gf[kc], ldB(wihx, (32 + c) * 4 + kc, lane), gn);
      }
      const int col = c * 16 + cl;
      float br_ = b_hh[col], bz_ = b_hh[256 + col], bn_ = b_hh[512 + col];
      f32x4 hr = {br_, br_, br_, br_}, hz = {bz_, bz_, bz_, bz_}, hn = {bn_, bn_, bn_, bn_};
#pragma unroll
      for (int kc = 0; kc < 8; kc++) {
        hr = mfma16(hf[kc], ldB(whh, (c)      * 8 + kc, lane), hr);
        hz = mfma16(hf[kc], ldB(whh, (16 + c) * 8 + kc, lane), hz);
        hn = mfma16(hf[kc], ldB(whh, (32 + c) * 8 + kc, lane), hn);
      }
#pragma unroll
      for (int j = 0; j < 4; j++) {
        const int row = rq + j;
        float rr = sigm(gr[j] + hr[j]);
        float zz = sigm(gz[j] + hz[j]);
        float nn = tanhx(gn[j] + rr * hn[j]);
        float hpv = cvt_f32(hp_s[row][col]);
        h_s[row][col] = (1.f - zz) * nn + zz * hpv;
      }
    }
    __syncthreads();
  }

  // epilogue: y_out / y_score
  if (tid < 16) {
    float acc = 0.f;
    for (int k = 0; k < H_; k++) acc += h_s[tid][k] * W_fc[k];
    float yv = acc + b_fc[0];
    out[YOUT_O + b0 + tid] = yv;
    out[YSC_O + b0 + tid] = 1.f / (1.f + __expf(-yv));
  }
  red_s[tid] = loss_acc;
  __syncthreads();
  for (int s = 128; s; s >>= 1) {
    if (tid < s) red_s[tid] += red_s[tid + s];
    __syncthreads();
  }
  if (tid == 0) {
    float* lp = reinterpret_cast<float*>(wsu + WS_LOSSP / 2);
    lp[blockIdx.x] = red_s[0];
  }
}

// ---------------- K3: deterministic loss reduction ----------------
__global__ void k3_loss(const float* __restrict__ lossp, float* __restrict__ out) {
  if (threadIdx.x == 0) {
    float s = 0.f;
    for (int i = 0; i < 32; i++) s += lossp[i];
    out[LOSS_O] = s;
  }
}

extern "C" void kernel_launch(void* const* d_in, const int* in_sizes, int n_in,
                              void* d_out, int out_size, void* d_ws, size_t ws_size,
                              hipStream_t stream) {
  (void)in_sizes; (void)n_in; (void)out_size; (void)ws_size;
  const float* x      = (const float*)d_in[0];
  const float* xhat   = (const float*)d_in[1];
  const float* u      = (const float*)d_in[2];
  const float* m      = (const float*)d_in[3];
  const float* d      = (const float*)d_in[4];
  const float* W_td   = (const float*)d_in[6];
  const float* b_td   = (const float*)d_in[7];
  const float* W_hist = (const float*)d_in[8];
  const float* b_hist = (const float*)d_in[9];
  const float* W_v    = (const float*)d_in[10];
  const float* b_v    = (const float*)d_in[11];
  const float* W_r    = (const float*)d_in[12];
  const float* b_r    = (const float*)d_in[13];
  const float* W_u    = (const float*)d_in[14];
  const float* b_u    = (const float*)d_in[15];
  const float* conv_w = (const float*)d_in[16];
  const float* conv_b = (const float*)d_in[17];
  const float* W_ih   = (const float*)d_in[18];
  const float* b_ih   = (const float*)d_in[19];
  const float* W_hh   = (const float*)d_in[20];
  const float* b_hh   = (const float*)d_in[21];
  const float* W_fc   = (const float*)d_in[22];
  const float* b_fc   = (const float*)d_in[23];
  float* out = (float*)d_out;
  u16* wsu = (u16*)d_ws;
  float* msum = (float*)d_ws;
  const float* lossp = (const float*)((char*)d_ws + WS_LOSSP);

  hipLaunchKernelGGL(k0_pack, dim3(244), dim3(256), 0, stream,
                     W_td, W_u, W_v, W_r, W_hist, W_ih, W_hh, msum, wsu);
  hipLaunchKernelGGL(k2_pre, dim3(416), dim3(256), 0, stream,
                     x, xhat, u, m, d, b_td, b_u, b_v, b_r, b_ih, msum, out, wsu);
  hipLaunchKernelGGL(k_seq, dim3(32), dim3(256), 0, stream,
                     x, m, b_hist, b_hh, conv_w, conv_b, W_fc, b_fc, msum, out, wsu);
  hipLaunchKernelGGL(k3_loss, dim3(1), dim3(64), 0, stream, lossp, out);
}

// Round 2
// 1836.559 us; speedup vs baseline: 2.5025x; 2.5025x over previous
//
#include <hip/hip_runtime.h>

typedef unsigned short u16;
typedef unsigned int   u32;
typedef unsigned char  u8;
typedef unsigned long long u64;
typedef long i64;
typedef __attribute__((ext_vector_type(8))) short s16x8;
typedef __attribute__((ext_vector_type(4))) float f32x4;

#define DEV static __device__ __forceinline__

constexpr int B_ = 512, T_ = 200, V_ = 99, H_ = 256;
constexpr int TV_ = T_ * V_;

// d_out f32 element offsets: (x_imp, y_out, y_score, x_loss, xus, xrs)
constexpr long long XIMP_O = 0;
constexpr long long YOUT_O = 10137600;
constexpr long long YSC_O  = 10138112;
constexpr long long LOSS_O = 10138624;
constexpr long long XUS_O  = 10138625;
constexpr long long XRS_O  = 20276225;

// workspace byte offsets
constexpr long long WS_MSUM  = 0;                               // 200 f32
constexpr long long WS_GAMMA = 1024;                            // [T][B][H] bf16
constexpr long long WS_XRPRE = WS_GAMMA + 2ll * T_ * B_ * H_;   // [T][B][V] bf16
constexpr long long WS_GIPRE = WS_XRPRE + 2ll * T_ * B_ * V_;   // [T][32][48][64][4] bf16 (C-frag layout)
constexpr long long WS_WTD   = WS_GIPRE + 2ll * T_ * 32 * 48 * 256;
constexpr long long WS_WU    = WS_WTD   + 64ll  * 1024;
constexpr long long WS_WV    = WS_WU    + 28ll  * 1024;
constexpr long long WS_WR    = WS_WV    + 28ll  * 1024;
constexpr long long WS_WHIST = WS_WR    + 28ll  * 1024;
constexpr long long WS_WIHX  = WS_WHIST + 56ll  * 1024;
constexpr long long WS_WIHM  = WS_WIHX  + 192ll * 1024;
constexpr long long WS_WHH   = WS_WIHM  + 192ll * 1024;         // 384KB region, reused for fp8 packs
constexpr long long WS_LOSSP = WS_WHH   + 384ll * 1024;         // 32 f32
// fp8 packs live inside the (no longer used for bf16) WS_WHH region:
constexpr long long WS_WIHX8 = WS_WHH;                          // 48 tiles * 4 chunks * 64 lanes * 8B = 96KB
constexpr long long WS_WHH8  = WS_WHH + 98304;                  // 48 tiles * 8 chunks * 64 lanes * 8B = 192KB

DEV u16 cvt_bf16(float f) {
  union { float f; u32 u; } v; v.f = f;
  u32 u = v.u;
  return (u16)((u + 0x7fffu + ((u >> 16) & 1u)) >> 16);
}
DEV float cvt_f32(u16 h) {
  union { u32 u; float f; } v; v.u = ((u32)h) << 16;
  return v.f;
}
// OCP e4m3fn encoder (RNE). Inputs here are always finite, |v| << 448.
DEV u32 enc_e4m3(float f) {
  union { float f; u32 u; } v; v.f = f;
  u32 sign = (v.u >> 24) & 0x80u;
  v.u &= 0x7fffffffu;
  float a = fminf(v.f, 448.f);
  if (a < 0.015625f) {                       // subnormal: multiples of 2^-9
    int mq = (int)rintf(a * 512.f);          // 0..8 ; 8 == min normal 0x08
    return sign | (u32)mq;
  }
  union { float f; u32 u; } w; w.f = a;
  u32 lsb = (w.u >> 20) & 1u;
  u32 r = w.u + 0x7FFFFu + lsb;
  u32 E = ((r >> 23) & 0xffu) - 120u;        // -127 + 7
  u32 M = (r >> 20) & 7u;
  if (E >= 16u) { E = 15u; M = 6u; }
  return sign | (E << 3) | M;
}
DEV f32x4 mfma16(s16x8 a, s16x8 b, f32x4 c) {
  return __builtin_amdgcn_mfma_f32_16x16x32_bf16(a, b, c, 0, 0, 0);
}
DEV f32x4 mfma8(i64 a, i64 b, f32x4 c) {
  return __builtin_amdgcn_mfma_f32_16x16x32_fp8_fp8(a, b, c, 0, 0, 0);
}
// A-fragment from LDS row-major [16][stride] (u16 units): lane -> row=lane&15, k=(lane>>4)*8+j
DEV s16x8 ldsA(const u16* base, int stride, int lane, int kc) {
  return *reinterpret_cast<const s16x8*>(base + (lane & 15) * stride + kc * 32 + ((lane >> 4) << 3));
}
// B-fragment from packed global weights
DEV s16x8 ldB(const u16* w, int frag, int lane) {
  return *reinterpret_cast<const s16x8*>(w + ((long long)frag * 64 + lane) * 8);
}
DEV f32x4 unpack_bf4(const u16* p) {
  const u32* q = reinterpret_cast<const u32*>(p);
  u32 a = q[0], b = q[1];
  return (f32x4){cvt_f32((u16)(a & 0xffffu)), cvt_f32((u16)(a >> 16)),
                 cvt_f32((u16)(b & 0xffffu)), cvt_f32((u16)(b >> 16))};
}
DEV f32x4 unpack_u64(u64 v) {
  return (f32x4){cvt_f32((u16)(v & 0xffffu)), cvt_f32((u16)((v >> 16) & 0xffffu)),
                 cvt_f32((u16)((v >> 32) & 0xffffu)), cvt_f32((u16)((v >> 48) & 0xffffu))};
}
DEV float sigm(float v) { return 1.f / (1.f + __expf(-v)); }
DEV float tanhx(float v) {
  float e = __expf(-2.f * fabsf(v));
  float t = (1.f - e) / (1.f + e);
  return v < 0.f ? -t : t;
}

// ---------------- K0: pack weights to bf16 MFMA-B fragment layout; zero msum ----------------
__global__ __launch_bounds__(256) void k0_pack(
    const float* __restrict__ W_td, const float* __restrict__ W_u, const float* __restrict__ W_v,
    const float* __restrict__ W_r, const float* __restrict__ W_hist, const float* __restrict__ W_ih,
    float* __restrict__ msum, u16* __restrict__ wsu) {
  if (blockIdx.x == 147) {
    if (threadIdx.x < T_) msum[threadIdx.x] = 0.f;
    return;
  }
  int frag = blockIdx.x * 4 + (threadIdx.x >> 6);
  int lane = threadIdx.x & 63;
  const float* src; long long off; int KC, koff, kmax, nmax, stride, diag = 0, f;
  if (frag < 64)       { f = frag;       src = W_td;   off = WS_WTD;   KC = 4; stride = 99;  koff = 0;  kmax = 99;  nmax = 256; }
  else if (frag < 92)  { f = frag - 64;  src = W_u;    off = WS_WU;    KC = 4; stride = 99;  koff = 0;  kmax = 99;  nmax = 99;  }
  else if (frag < 120) { f = frag - 92;  src = W_v;    off = WS_WV;    KC = 4; stride = 99;  koff = 0;  kmax = 99;  nmax = 99;  diag = 1; }
  else if (frag < 148) { f = frag - 120; src = W_r;    off = WS_WR;    KC = 4; stride = 99;  koff = 0;  kmax = 99;  nmax = 99;  diag = 1; }
  else if (frag < 204) { f = frag - 148; src = W_hist; off = WS_WHIST; KC = 8; stride = 256; koff = 0;  kmax = 256; nmax = 99;  }
  else if (frag < 396) { f = frag - 204; src = W_ih;   off = WS_WIHX;  KC = 4; stride = 198; koff = 0;  kmax = 99;  nmax = 768; }
  else if (frag < 588) { f = frag - 396; src = W_ih;   off = WS_WIHM;  KC = 4; stride = 198; koff = 99; kmax = 99;  nmax = 768; }
  else return;
  int nt = f / KC, kc = f % KC;
  int n = nt * 16 + (lane & 15);
  u16* dst = wsu + off / 2 + ((long long)f * 64 + lane) * 8;
#pragma unroll
  for (int j = 0; j < 8; j++) {
    int k = kc * 32 + ((lane >> 4) << 3) + j;
    float v = 0.f;
    if (k < kmax && n < nmax && !(diag && k == n)) v = src[(long long)n * stride + koff + k];
    dst[j] = cvt_bf16(v);
  }
}

// ---------------- K0b: pack W_ih(x-part) and W_hh to fp8 e4m3 B-fragments (scaled x16) ----------------
__global__ __launch_bounds__(256) void k0b_pack8(
    const float* __restrict__ W_ih, const float* __restrict__ W_hh, u8* __restrict__ ws8) {
  int frag = blockIdx.x * 4 + (threadIdx.x >> 6);
  int lane = threadIdx.x & 63;
  u64 r = 0;
  if (frag < 192) {                // wihx fp8: tile 0..47, kc 0..3 (K=99 pad 128)
    int tile = frag >> 2;
    int kc = frag & 3;
    int n = tile * 16 + (lane & 15);
#pragma unroll
    for (int j = 0; j < 8; j++) {
      int k = kc * 32 + ((lane >> 4) << 3) + j;
      float v = (k < 99) ? W_ih[(long long)n * 198 + k] * 16.f : 0.f;
      r |= (u64)enc_e4m3(v) << (8 * j);
    }
    *reinterpret_cast<u64*>(ws8 + WS_WIHX8 + ((long long)frag * 64 + lane) * 8) = r;
  } else if (frag < 576) {         // whh fp8: tile 0..47, kc 0..7 (K=256)
    int f = frag - 192;
    int tile = f >> 3;
    int kc = f & 7;
    int n = tile * 16 + (lane & 15);
#pragma unroll
    for (int j = 0; j < 8; j++) {
      int k = kc * 32 + ((lane >> 4) << 3) + j;
      r |= (u64)enc_e4m3(W_hh[(long long)n * 256 + k] * 16.f) << (8 * j);
    }
    *reinterpret_cast<u64*>(ws8 + WS_WHH8 + ((long long)f * 64 + lane) * 8) = r;
  }
}

// ---------------- K2: parallel precompute: gamma, xus(out), xr_pre, gi_pre, msum ----------------
__global__ __launch_bounds__(256) void k2_pre(
    const float* __restrict__ x, const float* __restrict__ xh, const float* __restrict__ uu,
    const float* __restrict__ m, const float* __restrict__ dd,
    const float* __restrict__ b_td, const float* __restrict__ b_u, const float* __restrict__ b_v,
    const float* __restrict__ b_r, const float* __restrict__ b_ih,
    float* __restrict__ msum, float* __restrict__ out, u16* __restrict__ wsu) {
  __shared__ __align__(16) u16 Abuf[4][16][136];
  const int tid = threadIdx.x, w = tid >> 6, lane = tid & 63;
  const int bc = blockIdx.x & 31, tg = blockIdx.x >> 5;
  const int b0 = bc * 16;
  const int cl = lane & 15, rq = (lane >> 4) << 2;
  const u16* wtd  = wsu + WS_WTD / 2;
  const u16* wu   = wsu + WS_WU / 2;
  const u16* wv   = wsu + WS_WV / 2;
  const u16* wr   = wsu + WS_WR / 2;
  const u16* wihx = wsu + WS_WIHX / 2;
  const u16* wihm = wsu + WS_WIHM / 2;
  u16* gam = wsu + WS_GAMMA / 2;
  u16* xrp = wsu + WS_XRPRE / 2;
  u16* gip = wsu + WS_GIPRE / 2;

  for (int it = 0; it < 4; it++) {
    const int t = tg * 16 + w * 4 + it;
    if (t >= T_) break;
    s16x8 fd[4], fu[4], fxb[4], fmx[4], fm[4];
    float mpart = 0.f;
#define STAGE(MODE, FR)                                                              \
    {                                                                                \
      for (int idx = lane; idx < 2048; idx += 64) {                                  \
        int row = idx >> 7, col = idx & 127; float v = 0.f;                          \
        if (col < V_) {                                                              \
          long long g = (long long)(b0 + row) * TV_ + (long long)t * V_ + col;       \
          if (MODE == 0) v = dd[g];                                                  \
          else if (MODE == 1) v = uu[g];                                             \
          else if (MODE == 2) { float mm = m[g]; v = mm * x[g] + (1.f - mm) * xh[g]; } \
          else if (MODE == 3) { v = m[g] * x[g]; }                                   \
          else { v = m[g]; mpart += v; }                                             \
        }                                                                            \
        Abuf[w][row][col] = cvt_bf16(v);                                             \
      }                                                                              \
      for (int kc = 0; kc < 4; kc++) FR[kc] = ldsA(&Abuf[w][0][0], 136, lane, kc);   \
    }
    STAGE(0, fd) STAGE(1, fu) STAGE(2, fxb) STAGE(3, fmx) STAGE(4, fm)
#undef STAGE
    float mp = mpart;
#pragma unroll
    for (int s = 32; s; s >>= 1) mp += __shfl_xor(mp, s);
    if (lane == 0) atomicAdd(&msum[t], mp);

    // V-wide GEMMs: unc / xu / xr_pre
    for (int nt = 0; nt < 7; nt++) {
      int col = nt * 16 + cl;
      float bu_ = 0.f, bv_ = 0.f, br_ = 0.f;
      if (col < V_) { bu_ = b_u[col]; bv_ = b_v[col]; br_ = b_r[col]; }
      f32x4 au = {bu_, bu_, bu_, bu_}, av = {bv_, bv_, bv_, bv_}, ar = {br_, br_, br_, br_};
#pragma unroll
      for (int kc = 0; kc < 4; kc++) {
        au = mfma16(fu[kc],  ldB(wu, nt * 4 + kc, lane), au);
        av = mfma16(fxb[kc], ldB(wv, nt * 4 + kc, lane), av);
        ar = mfma16(fmx[kc], ldB(wr, nt * 4 + kc, lane), ar);
      }
      if (col < V_) {
#pragma unroll
        for (int j = 0; j < 4; j++) {
          int b = b0 + rq + j;
          float unc = __expf(-fmaxf(au[j], 0.f));
          out[XUS_O + (long long)b * TV_ + (long long)t * V_ + col] = av[j] * unc;
          xrp[((long long)t * B_ + b) * V_ + col] = cvt_bf16(ar[j]);
        }
      }
    }
    // gi_pre (stored in C-fragment layout for the scan kernel)
    for (int nt = 0; nt < 48; nt++) {
      int col = nt * 16 + cl;
      float bi = b_ih[col];
      f32x4 a = {bi, bi, bi, bi};
#pragma unroll
      for (int kc = 0; kc < 4; kc++) {
        a = mfma16(fmx[kc], ldB(wihx, nt * 4 + kc, lane), a);
        a = mfma16(fm[kc],  ldB(wihm, nt * 4 + kc, lane), a);
      }
      u32 p0 = (u32)cvt_bf16(a[0]) | ((u32)cvt_bf16(a[1]) << 16);
      u32 p1 = (u32)cvt_bf16(a[2]) | ((u32)cvt_bf16(a[3]) << 16);
      u32* gp = reinterpret_cast<u32*>(gip + (((long long)t * 32 + bc) * 48 + nt) * 256 + (long long)lane * 4);
      gp[0] = p0; gp[1] = p1;
    }
    // gamma
    for (int nt = 0; nt < 16; nt++) {
      int col = nt * 16 + cl;
      float bt = b_td[col];
      f32x4 a = {bt, bt, bt, bt};
#pragma unroll
      for (int kc = 0; kc < 4; kc++) a = mfma16(fd[kc], ldB(wtd, nt * 4 + kc, lane), a);
#pragma unroll
      for (int j = 0; j < 4; j++) {
        int b = b0 + rq + j;
        gam[((long long)t * B_ + b) * H_ + col] = cvt_bf16(__expf(-fmaxf(a[j], 0.f)));
      }
    }
  }
}

// ---------------- K_SEQ: persistent recurrent scan; 32 WGs x 512 threads (8 waves) ----------------
// Resident: W_hh / W_ihx as fp8 (x16) in registers; W_hist / W_r bf16 in LDS.
__global__ __launch_bounds__(512, 2) void k_seq(
    const float* __restrict__ x, const float* __restrict__ m,
    const float* __restrict__ b_hist, const float* __restrict__ b_hh,
    const float* __restrict__ conv_w, const float* __restrict__ conv_b,
    const float* __restrict__ W_fc, const float* __restrict__ b_fc,
    const float* __restrict__ msum, float* out, u16* wsu) {
  __shared__ __align__(16) float h_s[16][264];
  __shared__ __align__(16) u16 hp_s[16][264];
  __shared__ __align__(16) u8  hp8_s[16 * 264];
  __shared__ __align__(16) u16 e_s[16][136];
  __shared__ __align__(16) u8  g8_s[16 * 136];
  __shared__ __align__(16) u16 whist_l[56 * 512];   // 56KB
  __shared__ __align__(16) u16 wr_l[28 * 512];      // 28KB
  __shared__ float red_s[512];

  const int tid = threadIdx.x, w = tid >> 6, lane = tid & 63;
  const int cl = lane & 15, rq = (lane >> 4) << 2;
  const int b0 = blockIdx.x * 16;

  // --- one-time LDS init ---
  for (int i = tid; i < 16 * 264; i += 512) h_s[i / 264][i % 264] = 0.f;
  for (int i = tid; i < 16 * 136; i += 512) e_s[i / 136][i % 136] = 0;
  for (int i = tid; i < 16 * 136; i += 512) g8_s[i] = 0;
  {
    const u32* src = reinterpret_cast<const u32*>(wsu + WS_WHIST / 2);
    u32* dst = reinterpret_cast<u32*>(whist_l);
    for (int i = tid; i < 14336; i += 512) dst[i] = src[i];
    const u32* src2 = reinterpret_cast<const u32*>(wsu + WS_WR / 2);
    u32* dst2 = reinterpret_cast<u32*>(wr_l);
    for (int i = tid; i < 7168; i += 512) dst2[i] = src2[i];
  }

  // --- resident fp8 weights (per wave: its 2 column-tiles x 3 gates) ---
  const u8* ws8 = reinterpret_cast<const u8*>(wsu);
  const u64* wx8 = reinterpret_cast<const u64*>(ws8 + WS_WIHX8);
  const u64* wh8 = reinterpret_cast<const u64*>(ws8 + WS_WHH8);
  i64 wihx_r[2][3][4];
  i64 whh_r[2][3][8];
#pragma unroll
  for (int ct = 0; ct < 2; ct++) {
#pragma unroll
    for (int gg = 0; gg < 3; gg++) {
      const int c = gg * 16 + 2 * w + ct;
#pragma unroll
      for (int kc = 0; kc < 4; kc++) wihx_r[ct][gg][kc] = (i64)wx8[(long long)(c * 4 + kc) * 64 + lane];
#pragma unroll
      for (int kc = 0; kc < 8; kc++) whh_r[ct][gg][kc]  = (i64)wh8[(long long)(c * 8 + kc) * 64 + lane];
    }
  }
  // --- bias / const preload ---
  float bhh_r[2][3];
#pragma unroll
  for (int ct = 0; ct < 2; ct++) {
    const int col = (2 * w + ct) * 16 + cl;
    bhh_r[ct][0] = b_hh[col];
    bhh_r[ct][1] = b_hh[256 + col];
    bhh_r[ct][2] = b_hh[512 + col];
  }
  float bh = 0.f;
  if (w < 7) { const int col = w * 16 + cl; if (col < V_) bh = b_hist[col]; }
  const float cw0 = conv_w[0], cw1 = conv_w[1], cb = conv_b[0];
  const u16* gamp = wsu + WS_GAMMA / 2;
  const u16* xrp  = wsu + WS_XRPRE / 2;
  const u64* gipb = reinterpret_cast<const u64*>(wsu + WS_GIPRE / 2);
  constexpr float inv128 = 1.f / 128.f;

  // gamma double-buffer (per-thread 8 values)
  const int r1 = tid >> 5, c1 = (tid & 31) << 3;
  u32 g4[4];
  {
    const u32* gp = reinterpret_cast<const u32*>(gamp + ((long long)(b0 + r1)) * H_ + c1);
    g4[0] = gp[0]; g4[1] = gp[1]; g4[2] = gp[2]; g4[3] = gp[3];
  }
  float loss_acc = 0.f;
  __syncthreads();

  for (int t = 0; t < T_; t++) {
    // ---- stream prefetch (no in-step deps) ----
    u64 gipr[2][3];
    {
      const u64* gb = gipb + (((long long)t * 32 + blockIdx.x) * 48) * 64 + lane;
#pragma unroll
      for (int ct = 0; ct < 2; ct++)
#pragma unroll
        for (int gg = 0; gg < 3; gg++)
          gipr[ct][gg] = gb[(long long)(gg * 16 + 2 * w + ct) * 64];
    }
    float xj[4] = {0.f, 0.f, 0.f, 0.f}, mj[4] = {0.f, 0.f, 0.f, 0.f}, xuv[4] = {0.f, 0.f, 0.f, 0.f};
    u16 xrpv[4] = {0, 0, 0, 0};
    if (w < 7) {
      const int col = w * 16 + cl;
      if (col < V_) {
#pragma unroll
        for (int j = 0; j < 4; j++) {
          const long long g = (long long)(b0 + rq + j) * TV_ + (long long)t * V_ + col;
          xj[j] = x[g]; mj[j] = m[g];
          xuv[j] = out[XUS_O + g];
          xrpv[j] = xrp[((long long)t * B_ + b0 + rq + j) * V_ + col];
        }
      }
    }

    // ---- S1: hp = h * gamma_t (bf16 + fp8(x8)) ----
    {
      u32 hp32[4]; u64 hp8v = 0;
#pragma unroll
      for (int k = 0; k < 4; k++) {
        const u32 gw = g4[k];
        const float f0 = h_s[r1][c1 + 2 * k]     * cvt_f32((u16)(gw & 0xffffu));
        const float f1 = h_s[r1][c1 + 2 * k + 1] * cvt_f32((u16)(gw >> 16));
        hp32[k] = (u32)cvt_bf16(f0) | ((u32)cvt_bf16(f1) << 16);
        hp8v |= (u64)enc_e4m3(f0 * 8.f) << (16 * k);
        hp8v |= (u64)enc_e4m3(f1 * 8.f) << (16 * k + 8);
      }
      u32* hpd = reinterpret_cast<u32*>(&hp_s[r1][c1]);
      hpd[0] = hp32[0]; hpd[1] = hp32[1]; hpd[2] = hp32[2]; hpd[3] = hp32[3];
      *reinterpret_cast<u64*>(&hp8_s[r1 * 264 + c1]) = hp8v;
    }
    __syncthreads();

    // ---- gh chains (fp8, resident whh) ----
    f32x4 accA[2][2];   // r,z gates: whh + wihx accumulate together
    f32x4 accNh[2];     // n gate, gh part (multiplied by r later)
    f32x4 accNx[2];     // n gate, gi-correction part
#pragma unroll
    for (int ct = 0; ct < 2; ct++) {
      accA[ct][0] = (f32x4){0.f, 0.f, 0.f, 0.f};
      accA[ct][1] = (f32x4){0.f, 0.f, 0.f, 0.f};
      accNh[ct]   = (f32x4){0.f, 0.f, 0.f, 0.f};
      accNx[ct]   = (f32x4){0.f, 0.f, 0.f, 0.f};
    }
#pragma unroll
    for (int kc = 0; kc < 8; kc++) {
      const i64 a = *reinterpret_cast<const i64*>(&hp8_s[(lane & 15) * 264 + kc * 32 + ((lane >> 4) << 3)]);
#pragma unroll
      for (int ct = 0; ct < 2; ct++) {
        accA[ct][0] = mfma8(a, whh_r[ct][0][kc], accA[ct][0]);
        accA[ct][1] = mfma8(a, whh_r[ct][1][kc], accA[ct][1]);
        accNh[ct]   = mfma8(a, whh_r[ct][2][kc], accNh[ct]);
      }
    }

    // ---- S2a: x_h = hp @ W_hist^T + b ; e = (1-m)*x_h ----
    if (w < 7) {
      const int col = w * 16 + cl;
      f32x4 a = {bh, bh, bh, bh};
#pragma unroll
      for (int kc = 0; kc < 8; kc++) {
        const s16x8 hfk = ldsA(&hp_s[0][0], 264, lane, kc);
        a = mfma16(hfk, *reinterpret_cast<const s16x8*>(&whist_l[(w * 8 + kc) * 512 + lane * 8]), a);
      }
      if (col < V_) {
#pragma unroll
        for (int j = 0; j < 4; j++) e_s[rq + j][col] = cvt_bf16((1.f - mj[j]) * a[j]);
      }
    }
    __syncthreads();

    // ---- S2b: xr, x_comb, loss, x_imp, xrs, g8 ----
    const float inv_ms = 1.f / (msum[t] + 1e-5f);
    if (w < 7) {
      const int col = w * 16 + cl;
      f32x4 a = {0.f, 0.f, 0.f, 0.f};
#pragma unroll
      for (int kc = 0; kc < 4; kc++) {
        const s16x8 efk = ldsA(&e_s[0][0], 136, lane, kc);
        a = mfma16(efk, *reinterpret_cast<const s16x8*>(&wr_l[(w * 4 + kc) * 512 + lane * 8]), a);
      }
      if (col < V_) {
#pragma unroll
        for (int j = 0; j < 4; j++) {
          const int row = rq + j;
          const long long g = (long long)(b0 + row) * TV_ + (long long)t * V_ + col;
          const float xrv = a[j] + cvt_f32(xrpv[j]);
          const float xc = cw0 * xuv[j] + cw1 * xrv + cb;
          loss_acc += fabsf(xj[j] - xc) * mj[j] * inv_ms;
          out[XIMP_O + g] = mj[j] * xj[j] + (1.f - mj[j]) * xc;
          out[XRS_O + g] = xrv;
          g8_s[row * 136 + col] = (u8)enc_e4m3((1.f - mj[j]) * xc * 8.f);
        }
      }
    }
    __syncthreads();

    // ---- gi corrections (fp8, resident wihx) + GRU update ----
#pragma unroll
    for (int kc = 0; kc < 4; kc++) {
      const i64 a = *reinterpret_cast<const i64*>(&g8_s[(lane & 15) * 136 + kc * 32 + ((lane >> 4) << 3)]);
#pragma unroll
      for (int ct = 0; ct < 2; ct++) {
        accA[ct][0] = mfma8(a, wihx_r[ct][0][kc], accA[ct][0]);
        accA[ct][1] = mfma8(a, wihx_r[ct][1][kc], accA[ct][1]);
        accNx[ct]   = mfma8(a, wihx_r[ct][2][kc], accNx[ct]);
      }
    }
#pragma unroll
    for (int ct = 0; ct < 2; ct++) {
      const int col = (2 * w + ct) * 16 + cl;
      const f32x4 gr = unpack_u64(gipr[ct][0]);
      const f32x4 gz = unpack_u64(gipr[ct][1]);
      const f32x4 gn = unpack_u64(gipr[ct][2]);
#pragma unroll
      for (int j = 0; j < 4; j++) {
        const int row = rq + j;
        const float rr = sigm(gr[j] + accA[ct][0][j] * inv128 + bhh_r[ct][0]);
        const float zz = sigm(gz[j] + accA[ct][1][j] * inv128 + bhh_r[ct][1]);
        const float ghn = accNh[ct][j] * inv128 + bhh_r[ct][2];
        const float nn = tanhx(gn[j] + accNx[ct][j] * inv128 + rr * ghn);
        const float hpv = cvt_f32(hp_s[row][col]);
        h_s[row][col] = (1.f - zz) * nn + zz * hpv;
      }
    }
    // prefetch next gamma (consumed next iteration, after the loop-end sync)
    if (t + 1 < T_) {
      const u32* gp = reinterpret_cast<const u32*>(gamp + ((long long)(t + 1) * B_ + b0 + r1) * H_ + c1);
      g4[0] = gp[0]; g4[1] = gp[1]; g4[2] = gp[2]; g4[3] = gp[3];
    }
    __syncthreads();
  }

  // ---- epilogue: y_out / y_score ----
  if (tid < 16) {
    float acc = 0.f;
    for (int k = 0; k < H_; k++) acc += h_s[tid][k] * W_fc[k];
    const float yv = acc + b_fc[0];
    out[YOUT_O + b0 + tid] = yv;
    out[YSC_O + b0 + tid] = 1.f / (1.f + __expf(-yv));
  }
  red_s[tid] = loss_acc;
  __syncthreads();
  for (int s = 256; s; s >>= 1) {
    if (tid < s) red_s[tid] += red_s[tid + s];
    __syncthreads();
  }
  if (tid == 0) {
    float* lp = reinterpret_cast<float*>(reinterpret_cast<char*>(wsu) + WS_LOSSP);
    lp[blockIdx.x] = red_s[0];
  }
}

// ---------------- K3: deterministic loss reduction ----------------
__global__ void k3_loss(const float* __restrict__ lossp, float* __restrict__ out) {
  if (threadIdx.x == 0) {
    float s = 0.f;
    for (int i = 0; i < 32; i++) s += lossp[i];
    out[LOSS_O] = s;
  }
}

extern "C" void kernel_launch(void* const* d_in, const int* in_sizes, int n_in,
                              void* d_out, int out_size, void* d_ws, size_t ws_size,
                              hipStream_t stream) {
  (void)in_sizes; (void)n_in; (void)out_size; (void)ws_size;
  const float* x      = (const float*)d_in[0];
  const float* xhat   = (const float*)d_in[1];
  const float* u      = (const float*)d_in[2];
  const float* m      = (const float*)d_in[3];
  const float* d      = (const float*)d_in[4];
  const float* W_td   = (const float*)d_in[6];
  const float* b_td   = (const float*)d_in[7];
  const float* W_hist = (const float*)d_in[8];
  const float* b_hist = (const float*)d_in[9];
  const float* W_v    = (const float*)d_in[10];
  const float* b_v    = (const float*)d_in[11];
  const float* W_r    = (const float*)d_in[12];
  const float* b_r    = (const float*)d_in[13];
  const float* W_u    = (const float*)d_in[14];
  const float* b_u    = (const float*)d_in[15];
  const float* conv_w = (const float*)d_in[16];
  const float* conv_b = (const float*)d_in[17];
  const float* W_ih   = (const float*)d_in[18];
  const float* b_ih   = (const float*)d_in[19];
  const float* W_hh   = (const float*)d_in[20];
  const float* b_hh   = (const float*)d_in[21];
  const float* W_fc   = (const float*)d_in[22];
  const float* b_fc   = (const float*)d_in[23];
  float* out = (float*)d_out;
  u16* wsu = (u16*)d_ws;
  float* msum = (float*)d_ws;
  const float* lossp = (const float*)((char*)d_ws + WS_LOSSP);

  hipLaunchKernelGGL(k0_pack, dim3(148), dim3(256), 0, stream,
                     W_td, W_u, W_v, W_r, W_hist, W_ih, msum, wsu);
  hipLaunchKernelGGL(k0b_pack8, dim3(144), dim3(256), 0, stream,
                     W_ih, W_hh, (u8*)d_ws);
  hipLaunchKernelGGL(k2_pre, dim3(416), dim3(256), 0, stream,
                     x, xhat, u, m, d, b_td, b_u, b_v, b_r, b_ih, msum, out, wsu);
  hipLaunchKernelGGL(k_seq, dim3(32), dim3(512), 0, stream,
                     x, m, b_hist, b_hh, conv_w, conv_b, W_fc, b_fc, msum, out, wsu);
  hipLaunchKernelGGL(k3_loss, dim3(1), dim3(64), 0, stream, lossp, out);
}

// Round 3
// 1758.749 us; speedup vs baseline: 2.6132x; 1.0442x over previous
//
#include <hip/hip_runtime.h>

typedef unsigned short u16;
typedef unsigned int   u32;
typedef unsigned char  u8;
typedef unsigned long long u64;
typedef long i64;
typedef __attribute__((ext_vector_type(8))) short s16x8;
typedef __attribute__((ext_vector_type(4))) float f32x4;

#define DEV static __device__ __forceinline__

constexpr int B_ = 512, T_ = 200, V_ = 99, H_ = 256;
constexpr int TV_ = T_ * V_;

// d_out f32 element offsets: (x_imp, y_out, y_score, x_loss, xus, xrs)
constexpr long long XIMP_O = 0;
constexpr long long YOUT_O = 10137600;
constexpr long long YSC_O  = 10138112;
constexpr long long LOSS_O = 10138624;
constexpr long long XUS_O  = 10138625;
constexpr long long XRS_O  = 20276225;

// workspace byte offsets
constexpr long long WS_MSUM  = 0;                               // 200 f32
constexpr long long WS_GAMMA = 1024;                            // [T][B][H] bf16
constexpr long long WS_XRPRE = WS_GAMMA + 2ll * T_ * B_ * H_;   // [T][B][V] bf16
constexpr long long WS_GIPRE = WS_XRPRE + 2ll * T_ * B_ * V_;   // [T][32][48][64][4] bf16 (C-frag layout)
constexpr long long WS_WTD   = WS_GIPRE + 2ll * T_ * 32 * 48 * 256;
constexpr long long WS_WU    = WS_WTD   + 64ll  * 1024;
constexpr long long WS_WV    = WS_WU    + 28ll  * 1024;
constexpr long long WS_WR    = WS_WV    + 28ll  * 1024;
constexpr long long WS_WHIST = WS_WR    + 28ll  * 1024;
constexpr long long WS_WIHX  = WS_WHIST + 56ll  * 1024;
constexpr long long WS_WIHM  = WS_WIHX  + 192ll * 1024;
constexpr long long WS_WHH   = WS_WIHM  + 192ll * 1024;         // 384KB region, reused for fp8 packs
constexpr long long WS_LOSSP = WS_WHH   + 384ll * 1024;         // 32 f32
// fp8 packs live inside the (no longer used for bf16) WS_WHH region:
constexpr long long WS_WIHX8 = WS_WHH;                          // 48 tiles * 4 chunks * 64 lanes * 8B = 96KB
constexpr long long WS_WHH8  = WS_WHH + 98304;                  // 48 tiles * 8 chunks * 64 lanes * 8B = 192KB

DEV u16 cvt_bf16(float f) {
  union { float f; u32 u; } v; v.f = f;
  u32 u = v.u;
  return (u16)((u + 0x7fffu + ((u >> 16) & 1u)) >> 16);
}
DEV float cvt_f32(u16 h) {
  union { u32 u; float f; } v; v.u = ((u32)h) << 16;
  return v.f;
}
// OCP e4m3fn encoder (RNE, full range incl. subnormal) - used in pack kernels only
DEV u32 enc_e4m3(float f) {
  union { float f; u32 u; } v; v.f = f;
  u32 sign = (v.u >> 24) & 0x80u;
  v.u &= 0x7fffffffu;
  float a = fminf(v.f, 448.f);
  if (a < 0.015625f) {
    int mq = (int)rintf(a * 512.f);
    return sign | (u32)mq;
  }
  union { float f; u32 u; } w; w.f = a;
  u32 lsb = (w.u >> 20) & 1u;
  u32 r = w.u + 0x7FFFFu + lsb;
  u32 E = ((r >> 23) & 0xffu) - 120u;
  u32 M = (r >> 20) & 7u;
  if (E >= 16u) { E = 15u; M = 6u; }
  return sign | (E << 3) | M;
}
// fast e4m3 encoder: |f| < 448 guaranteed, flush-to-zero below 2^-6 (RNE on mantissa)
DEV u32 enc8f(float f) {
  union { float ff; u32 u; } v; v.ff = f;
  u32 s = (v.u >> 24) & 0x80u;
  u32 a = v.u & 0x7fffffffu;
  u32 r = a + 0x7FFFFu + ((a >> 20) & 1u);
  if (r < 0x3C800000u) return s;
  return s | (((r >> 20) - 960u) & 0x7fu);
}
DEV f32x4 mfma16(s16x8 a, s16x8 b, f32x4 c) {
  return __builtin_amdgcn_mfma_f32_16x16x32_bf16(a, b, c, 0, 0, 0);
}
DEV f32x4 mfma8(i64 a, i64 b, f32x4 c) {
  return __builtin_amdgcn_mfma_f32_16x16x32_fp8_fp8(a, b, c, 0, 0, 0);
}
// A-fragment from LDS row-major [16][stride] (u16 units): lane -> row=lane&15, k=(lane>>4)*8+j
DEV s16x8 ldsA(const u16* base, int stride, int lane, int kc) {
  return *reinterpret_cast<const s16x8*>(base + (lane & 15) * stride + kc * 32 + ((lane >> 4) << 3));
}
// B-fragment from packed global weights
DEV s16x8 ldB(const u16* w, int frag, int lane) {
  return *reinterpret_cast<const s16x8*>(w + ((long long)frag * 64 + lane) * 8);
}
DEV f32x4 unpack_u64(u64 v) {
  return (f32x4){cvt_f32((u16)(v & 0xffffu)), cvt_f32((u16)((v >> 16) & 0xffffu)),
                 cvt_f32((u16)((v >> 32) & 0xffffu)), cvt_f32((u16)((v >> 48) & 0xffffu))};
}
DEV float sigm(float v) { return 1.f / (1.f + __expf(-v)); }
DEV float tanhx(float v) {
  float e = __expf(-2.f * fabsf(v));
  float t = (1.f - e) / (1.f + e);
  return v < 0.f ? -t : t;
}

// ---------------- K0: pack weights to bf16 MFMA-B fragment layout; zero msum ----------------
__global__ __launch_bounds__(256) void k0_pack(
    const float* __restrict__ W_td, const float* __restrict__ W_u, const float* __restrict__ W_v,
    const float* __restrict__ W_r, const float* __restrict__ W_hist, const float* __restrict__ W_ih,
    float* __restrict__ msum, u16* __restrict__ wsu) {
  if (blockIdx.x == 147) {
    if (threadIdx.x < T_) msum[threadIdx.x] = 0.f;
    return;
  }
  int frag = blockIdx.x * 4 + (threadIdx.x >> 6);
  int lane = threadIdx.x & 63;
  const float* src; long long off; int KC, koff, kmax, nmax, stride, diag = 0, f;
  if (frag < 64)       { f = frag;       src = W_td;   off = WS_WTD;   KC = 4; stride = 99;  koff = 0;  kmax = 99;  nmax = 256; }
  else if (frag < 92)  { f = frag - 64;  src = W_u;    off = WS_WU;    KC = 4; stride = 99;  koff = 0;  kmax = 99;  nmax = 99;  }
  else if (frag < 120) { f = frag - 92;  src = W_v;    off = WS_WV;    KC = 4; stride = 99;  koff = 0;  kmax = 99;  nmax = 99;  diag = 1; }
  else if (frag < 148) { f = frag - 120; src = W_r;    off = WS_WR;    KC = 4; stride = 99;  koff = 0;  kmax = 99;  nmax = 99;  diag = 1; }
  else if (frag < 204) { f = frag - 148; src = W_hist; off = WS_WHIST; KC = 8; stride = 256; koff = 0;  kmax = 256; nmax = 99;  }
  else if (frag < 396) { f = frag - 204; src = W_ih;   off = WS_WIHX;  KC = 4; stride = 198; koff = 0;  kmax = 99;  nmax = 768; }
  else if (frag < 588) { f = frag - 396; src = W_ih;   off = WS_WIHM;  KC = 4; stride = 198; koff = 99; kmax = 99;  nmax = 768; }
  else return;
  int nt = f / KC, kc = f % KC;
  int n = nt * 16 + (lane & 15);
  u16* dst = wsu + off / 2 + ((long long)f * 64 + lane) * 8;
#pragma unroll
  for (int j = 0; j < 8; j++) {
    int k = kc * 32 + ((lane >> 4) << 3) + j;
    float v = 0.f;
    if (k < kmax && n < nmax && !(diag && k == n)) v = src[(long long)n * stride + koff + k];
    dst[j] = cvt_bf16(v);
  }
}

// ---------------- K0b: pack W_ih(x-part) and W_hh to fp8 e4m3 B-fragments (scaled x16) ----------------
__global__ __launch_bounds__(256) void k0b_pack8(
    const float* __restrict__ W_ih, const float* __restrict__ W_hh, u8* __restrict__ ws8) {
  int frag = blockIdx.x * 4 + (threadIdx.x >> 6);
  int lane = threadIdx.x & 63;
  u64 r = 0;
  if (frag < 192) {                // wihx fp8: tile 0..47, kc 0..3 (K=99 pad 128)
    int tile = frag >> 2;
    int kc = frag & 3;
    int n = tile * 16 + (lane & 15);
#pragma unroll
    for (int j = 0; j < 8; j++) {
      int k = kc * 32 + ((lane >> 4) << 3) + j;
      float v = (k < 99) ? W_ih[(long long)n * 198 + k] * 16.f : 0.f;
      r |= (u64)enc_e4m3(v) << (8 * j);
    }
    *reinterpret_cast<u64*>(ws8 + WS_WIHX8 + ((long long)frag * 64 + lane) * 8) = r;
  } else if (frag < 576) {         // whh fp8: tile 0..47, kc 0..7 (K=256)
    int f = frag - 192;
    int tile = f >> 3;
    int kc = f & 7;
    int n = tile * 16 + (lane & 15);
#pragma unroll
    for (int j = 0; j < 8; j++) {
      int k = kc * 32 + ((lane >> 4) << 3) + j;
      r |= (u64)enc_e4m3(W_hh[(long long)n * 256 + k] * 16.f) << (8 * j);
    }
    *reinterpret_cast<u64*>(ws8 + WS_WHH8 + ((long long)f * 64 + lane) * 8) = r;
  }
}

// ---------------- K2: parallel precompute: gamma, xus(out), xr_pre, gi_pre, msum ----------------
// grid 1600: one wave per (batch-chunk bc in [0,32), t in [0,200))
__global__ __launch_bounds__(256) void k2_pre(
    const float* __restrict__ x, const float* __restrict__ xh, const float* __restrict__ uu,
    const float* __restrict__ m, const float* __restrict__ dd,
    const float* __restrict__ b_td, const float* __restrict__ b_u, const float* __restrict__ b_v,
    const float* __restrict__ b_r, const float* __restrict__ b_ih,
    float* __restrict__ msum, float* __restrict__ out, u16* __restrict__ wsu) {
  __shared__ __align__(16) u16 Abuf[4][16][136];
  const int tid = threadIdx.x, w = tid >> 6, lane = tid & 63;
  const int bc = blockIdx.x & 31, tg = blockIdx.x >> 5;
  const int b0 = bc * 16;
  const int cl = lane & 15, rq = (lane >> 4) << 2;
  const u16* wtd  = wsu + WS_WTD / 2;
  const u16* wu   = wsu + WS_WU / 2;
  const u16* wv   = wsu + WS_WV / 2;
  const u16* wr   = wsu + WS_WR / 2;
  const u16* wihx = wsu + WS_WIHX / 2;
  const u16* wihm = wsu + WS_WIHM / 2;
  u16* gam = wsu + WS_GAMMA / 2;
  u16* xrp = wsu + WS_XRPRE / 2;
  u16* gip = wsu + WS_GIPRE / 2;

  const int t = tg * 4 + w;
  s16x8 fd[4], fu[4], fxb[4], fmx[4], fm[4];
  float mpart = 0.f;
#define STAGE(MODE, FR)                                                              \
    {                                                                                \
      for (int idx = lane; idx < 2048; idx += 64) {                                  \
        int row = idx >> 7, col = idx & 127; float v = 0.f;                          \
        if (col < V_) {                                                              \
          long long g = (long long)(b0 + row) * TV_ + (long long)t * V_ + col;       \
          if (MODE == 0) v = dd[g];                                                  \
          else if (MODE == 1) v = uu[g];                                             \
          else if (MODE == 2) { float mm = m[g]; v = mm * x[g] + (1.f - mm) * xh[g]; } \
          else if (MODE == 3) { v = m[g] * x[g]; }                                   \
          else { v = m[g]; mpart += v; }                                             \
        }                                                                            \
        Abuf[w][row][col] = cvt_bf16(v);                                             \
      }                                                                              \
      for (int kc = 0; kc < 4; kc++) FR[kc] = ldsA(&Abuf[w][0][0], 136, lane, kc);   \
    }
  STAGE(0, fd) STAGE(1, fu) STAGE(2, fxb) STAGE(3, fmx) STAGE(4, fm)
#undef STAGE
  float mp = mpart;
#pragma unroll
  for (int s = 32; s; s >>= 1) mp += __shfl_xor(mp, s);
  if (lane == 0) atomicAdd(&msum[t], mp);

  // V-wide GEMMs: unc / xu / xr_pre
  for (int nt = 0; nt < 7; nt++) {
    int col = nt * 16 + cl;
    float bu_ = 0.f, bv_ = 0.f, br_ = 0.f;
    if (col < V_) { bu_ = b_u[col]; bv_ = b_v[col]; br_ = b_r[col]; }
    f32x4 au = {bu_, bu_, bu_, bu_}, av = {bv_, bv_, bv_, bv_}, ar = {br_, br_, br_, br_};
#pragma unroll
    for (int kc = 0; kc < 4; kc++) {
      au = mfma16(fu[kc],  ldB(wu, nt * 4 + kc, lane), au);
      av = mfma16(fxb[kc], ldB(wv, nt * 4 + kc, lane), av);
      ar = mfma16(fmx[kc], ldB(wr, nt * 4 + kc, lane), ar);
    }
    if (col < V_) {
#pragma unroll
      for (int j = 0; j < 4; j++) {
        int b = b0 + rq + j;
        float unc = __expf(-fmaxf(au[j], 0.f));
        out[XUS_O + (long long)b * TV_ + (long long)t * V_ + col] = av[j] * unc;
        xrp[((long long)t * B_ + b) * V_ + col] = cvt_bf16(ar[j]);
      }
    }
  }
  // gi_pre (stored in C-fragment layout for the scan kernel)
  for (int nt = 0; nt < 48; nt++) {
    int col = nt * 16 + cl;
    float bi = b_ih[col];
    f32x4 a = {bi, bi, bi, bi};
#pragma unroll
    for (int kc = 0; kc < 4; kc++) {
      a = mfma16(fmx[kc], ldB(wihx, nt * 4 + kc, lane), a);
      a = mfma16(fm[kc],  ldB(wihm, nt * 4 + kc, lane), a);
    }
    u32 p0 = (u32)cvt_bf16(a[0]) | ((u32)cvt_bf16(a[1]) << 16);
    u32 p1 = (u32)cvt_bf16(a[2]) | ((u32)cvt_bf16(a[3]) << 16);
    u32* gp = reinterpret_cast<u32*>(gip + (((long long)t * 32 + bc) * 48 + nt) * 256 + (long long)lane * 4);
    gp[0] = p0; gp[1] = p1;
  }
  // gamma
  for (int nt = 0; nt < 16; nt++) {
    int col = nt * 16 + cl;
    float bt = b_td[col];
    f32x4 a = {bt, bt, bt, bt};
#pragma unroll
    for (int kc = 0; kc < 4; kc++) a = mfma16(fd[kc], ldB(wtd, nt * 4 + kc, lane), a);
#pragma unroll
    for (int j = 0; j < 4; j++) {
      int b = b0 + rq + j;
      gam[((long long)t * B_ + b) * H_ + col] = cvt_bf16(__expf(-fmaxf(a[j], 0.f)));
    }
  }
}

// ---------------- K_SEQ: persistent recurrent scan; 32 WGs x 512 threads (8 waves) ----------------
// Resident: W_hh / W_ihx fp8 (x16) in registers (144 VGPR); W_hist / W_r bf16 in LDS.
// 3 barriers/step; gamma fused into the GRU update (no separate decay phase).
__global__ void __attribute__((amdgpu_flat_work_group_size(512, 512), amdgpu_waves_per_eu(2, 2)))
k_seq(
    const float* __restrict__ x, const float* __restrict__ m,
    const float* __restrict__ b_hist, const float* __restrict__ b_hh,
    const float* __restrict__ conv_w, const float* __restrict__ conv_b,
    const float* __restrict__ W_fc, const float* __restrict__ b_fc,
    const float* __restrict__ msum, float* out, u16* wsu) {
  __shared__ __align__(16) u16 hp_s[16][264];     // bf16 hp (row stride 264 u16)
  __shared__ __align__(16) u8  hp8_s[16 * 272];   // fp8 hp  (row stride 272 B, bank-pad)
  __shared__ __align__(16) u16 e_s[16][136];
  __shared__ __align__(16) u8  g8_s[16 * 144];    // row stride 144 B, bank-pad
  __shared__ __align__(16) u16 whist_l[56 * 512]; // 56KB
  __shared__ __align__(16) u16 wr_l[28 * 512];    // 28KB
  __shared__ __align__(16) float hf_s[16][268];   // final-step h (f32) for epilogue
  __shared__ float red_s[512];

  const int tid = threadIdx.x, w = tid >> 6, lane = tid & 63;
  const int cl = lane & 15, rq = (lane >> 4) << 2;
  const int b0 = blockIdx.x * 16;

  // --- one-time LDS init ---
  for (int i = tid; i < 16 * 264 / 2; i += 512) reinterpret_cast<u32*>(&hp_s[0][0])[i] = 0;
  for (int i = tid; i < 16 * 272 / 4; i += 512) reinterpret_cast<u32*>(hp8_s)[i] = 0;
  for (int i = tid; i < 16 * 136 / 2; i += 512) reinterpret_cast<u32*>(&e_s[0][0])[i] = 0;
  for (int i = tid; i < 16 * 144 / 4; i += 512) reinterpret_cast<u32*>(g8_s)[i] = 0;
  {
    const u32* src = reinterpret_cast<const u32*>(wsu + WS_WHIST / 2);
    u32* dst = reinterpret_cast<u32*>(whist_l);
    for (int i = tid; i < 14336; i += 512) dst[i] = src[i];
    const u32* src2 = reinterpret_cast<const u32*>(wsu + WS_WR / 2);
    u32* dst2 = reinterpret_cast<u32*>(wr_l);
    for (int i = tid; i < 7168; i += 512) dst2[i] = src2[i];
  }

  // --- resident fp8 weights (per wave: its 2 column-tiles x 3 gates) ---
  const u8* ws8 = reinterpret_cast<const u8*>(wsu);
  const u64* wx8 = reinterpret_cast<const u64*>(ws8 + WS_WIHX8);
  const u64* wh8 = reinterpret_cast<const u64*>(ws8 + WS_WHH8);
  i64 wihx_r[2][3][4];
  i64 whh_r[2][3][8];
#pragma unroll
  for (int ct = 0; ct < 2; ct++) {
#pragma unroll
    for (int gg = 0; gg < 3; gg++) {
      const int c = gg * 16 + 2 * w + ct;
#pragma unroll
      for (int kc = 0; kc < 4; kc++) wihx_r[ct][gg][kc] = (i64)wx8[(long long)(c * 4 + kc) * 64 + lane];
#pragma unroll
      for (int kc = 0; kc < 8; kc++) whh_r[ct][gg][kc]  = (i64)wh8[(long long)(c * 8 + kc) * 64 + lane];
    }
  }
  // --- bias / const preload ---
  float bhh_r[2][3];
#pragma unroll
  for (int ct = 0; ct < 2; ct++) {
    const int col = (2 * w + ct) * 16 + cl;
    bhh_r[ct][0] = b_hh[col];
    bhh_r[ct][1] = b_hh[256 + col];
    bhh_r[ct][2] = b_hh[512 + col];
  }
  float bh = 0.f;
  if (w < 7) { const int col = w * 16 + cl; if (col < V_) bh = b_hist[col]; }
  const float cw0 = conv_w[0], cw1 = conv_w[1], cb = conv_b[0];
  const u16* gamp = wsu + WS_GAMMA / 2;
  const u16* xrp  = wsu + WS_XRPRE / 2;
  const u64* gipb = reinterpret_cast<const u64*>(wsu + WS_GIPRE / 2);
  constexpr float inv128 = 1.f / 128.f;

  float hpr[2][4];   // this thread's hp values (f32, pre-rounding) at (rq+j, (2w+ct)*16+cl)
#pragma unroll
  for (int ct = 0; ct < 2; ct++)
#pragma unroll
    for (int j = 0; j < 4; j++) hpr[ct][j] = 0.f;

  float loss_acc = 0.f;
  const int vcol = w * 16 + cl;          // V-column for waves 0..6
  const bool vact = (w < 7) && (vcol < V_);
  __syncthreads();

  for (int t = 0; t < T_; t++) {
    const bool last = (t == T_ - 1);
    // ---- step-top: issue all global loads (consumed in P2/P3) ----
    u64 gipr[2][3];
    {
      const u64* gb = gipb + (((long long)t * 32 + blockIdx.x) * 48) * 64 + lane;
#pragma unroll
      for (int ct = 0; ct < 2; ct++)
#pragma unroll
        for (int gg = 0; gg < 3; gg++)
          gipr[ct][gg] = gb[(long long)(gg * 16 + 2 * w + ct) * 64];
    }
    u16 ga[2][4];      // gamma[t+1] at this thread's own (row,col) positions
    if (!last) {
#pragma unroll
      for (int ct = 0; ct < 2; ct++) {
        const int col = (2 * w + ct) * 16 + cl;
#pragma unroll
        for (int j = 0; j < 4; j++)
          ga[ct][j] = gamp[((long long)(t + 1) * B_ + b0 + rq + j) * H_ + col];
      }
    }
    float xj[4] = {0.f, 0.f, 0.f, 0.f}, mj[4] = {0.f, 0.f, 0.f, 0.f}, xuv[4] = {0.f, 0.f, 0.f, 0.f};
    u16 xrpv[4] = {0, 0, 0, 0};
    if (vact) {
#pragma unroll
      for (int j = 0; j < 4; j++) {
        const long long g = (long long)(b0 + rq + j) * TV_ + (long long)t * V_ + vcol;
        xj[j] = x[g]; mj[j] = m[g];
        xuv[j] = out[XUS_O + g];
        xrpv[j] = xrp[((long long)t * B_ + b0 + rq + j) * V_ + vcol];
      }
    }
    const float msv = msum[t];

    // ---- P1: gh chains (fp8, resident whh) + whist -> e ----
    f32x4 accA[2][2], accNh[2];
#pragma unroll
    for (int ct = 0; ct < 2; ct++) {
      accA[ct][0] = (f32x4){0.f, 0.f, 0.f, 0.f};
      accA[ct][1] = (f32x4){0.f, 0.f, 0.f, 0.f};
      accNh[ct]   = (f32x4){0.f, 0.f, 0.f, 0.f};
    }
#pragma unroll
    for (int kc = 0; kc < 8; kc++) {
      const i64 a = *reinterpret_cast<const i64*>(&hp8_s[(lane & 15) * 272 + kc * 32 + ((lane >> 4) << 3)]);
#pragma unroll
      for (int ct = 0; ct < 2; ct++) {
        accA[ct][0] = mfma8(a, whh_r[ct][0][kc], accA[ct][0]);
        accA[ct][1] = mfma8(a, whh_r[ct][1][kc], accA[ct][1]);
        accNh[ct]   = mfma8(a, whh_r[ct][2][kc], accNh[ct]);
      }
    }
    if (w < 7) {
      f32x4 a = {bh, bh, bh, bh};
#pragma unroll
      for (int kc = 0; kc < 8; kc++) {
        const s16x8 hfk = ldsA(&hp_s[0][0], 264, lane, kc);
        a = mfma16(hfk, *reinterpret_cast<const s16x8*>(&whist_l[(w * 8 + kc) * 512 + lane * 8]), a);
      }
      if (vact) {
#pragma unroll
        for (int j = 0; j < 4; j++) e_s[rq + j][vcol] = cvt_bf16((1.f - mj[j]) * a[j]);
      }
    }
    __syncthreads();

    // ---- P2: xr, x_comb, loss, x_imp, xrs, g8 ----
    if (w < 7) {
      f32x4 a = {0.f, 0.f, 0.f, 0.f};
#pragma unroll
      for (int kc = 0; kc < 4; kc++) {
        const s16x8 efk = ldsA(&e_s[0][0], 136, lane, kc);
        a = mfma16(efk, *reinterpret_cast<const s16x8*>(&wr_l[(w * 4 + kc) * 512 + lane * 8]), a);
      }
      if (vact) {
        float ls = 0.f;
#pragma unroll
        for (int j = 0; j < 4; j++) {
          const int row = rq + j;
          const long long g = (long long)(b0 + row) * TV_ + (long long)t * V_ + vcol;
          const float xrv = a[j] + cvt_f32(xrpv[j]);
          const float xc = cw0 * xuv[j] + cw1 * xrv + cb;
          ls += fabsf(xj[j] - xc) * mj[j];
          out[XIMP_O + g] = mj[j] * xj[j] + (1.f - mj[j]) * xc;
          out[XRS_O + g] = xrv;
          const float gv = fminf(fmaxf((1.f - mj[j]) * xc * 8.f, -440.f), 440.f);
          g8_s[row * 144 + vcol] = (u8)enc8f(gv);
        }
        loss_acc += ls / (msv + 1e-5f);
      }
    }
    __syncthreads();

    // ---- P3: gi corrections (fp8, resident wihx) + GRU update + fused gamma[t+1] ----
    f32x4 accNx[2];
    accNx[0] = (f32x4){0.f, 0.f, 0.f, 0.f};
    accNx[1] = (f32x4){0.f, 0.f, 0.f, 0.f};
#pragma unroll
    for (int kc = 0; kc < 4; kc++) {
      const i64 a = *reinterpret_cast<const i64*>(&g8_s[(lane & 15) * 144 + kc * 32 + ((lane >> 4) << 3)]);
#pragma unroll
      for (int ct = 0; ct < 2; ct++) {
        accA[ct][0] = mfma8(a, wihx_r[ct][0][kc], accA[ct][0]);
        accA[ct][1] = mfma8(a, wihx_r[ct][1][kc], accA[ct][1]);
        accNx[ct]   = mfma8(a, wihx_r[ct][2][kc], accNx[ct]);
      }
    }
#pragma unroll
    for (int ct = 0; ct < 2; ct++) {
      const int col = (2 * w + ct) * 16 + cl;
      const f32x4 gr = unpack_u64(gipr[ct][0]);
      const f32x4 gz = unpack_u64(gipr[ct][1]);
      const f32x4 gn = unpack_u64(gipr[ct][2]);
#pragma unroll
      for (int j = 0; j < 4; j++) {
        const int row = rq + j;
        const float rr = sigm(gr[j] + accA[ct][0][j] * inv128 + bhh_r[ct][0]);
        const float zz = sigm(gz[j] + accA[ct][1][j] * inv128 + bhh_r[ct][1]);
        const float ghn = accNh[ct][j] * inv128 + bhh_r[ct][2];
        const float nn = tanhx(gn[j] + accNx[ct][j] * inv128 + rr * ghn);
        const float hn = (1.f - zz) * nn + zz * hpr[ct][j];
        if (last) {
          hf_s[row][col] = hn;
          hpr[ct][j] = hn;
        } else {
          const float hpnew = hn * cvt_f32(ga[ct][j]);
          hpr[ct][j] = hpnew;
          hp_s[row][col] = cvt_bf16(hpnew);
          hp8_s[row * 272 + col] = (u8)enc8f(hpnew * 8.f);
        }
      }
    }
    __syncthreads();
  }

  // ---- epilogue: y_out / y_score ----
  if (tid < 16) {
    float acc = 0.f;
    for (int k = 0; k < H_; k++) acc += hf_s[tid][k] * W_fc[k];
    const float yv = acc + b_fc[0];
    out[YOUT_O + b0 + tid] = yv;
    out[YSC_O + b0 + tid] = 1.f / (1.f + __expf(-yv));
  }
  red_s[tid] = loss_acc;
  __syncthreads();
  for (int s = 256; s; s >>= 1) {
    if (tid < s) red_s[tid] += red_s[tid + s];
    __syncthreads();
  }
  if (tid == 0) {
    float* lp = reinterpret_cast<float*>(reinterpret_cast<char*>(wsu) + WS_LOSSP);
    lp[blockIdx.x] = red_s[0];
  }
}

// ---------------- K3: deterministic loss reduction ----------------
__global__ void k3_loss(const float* __restrict__ lossp, float* __restrict__ out) {
  if (threadIdx.x == 0) {
    float s = 0.f;
    for (int i = 0; i < 32; i++) s += lossp[i];
    out[LOSS_O] = s;
  }
}

extern "C" void kernel_launch(void* const* d_in, const int* in_sizes, int n_in,
                              void* d_out, int out_size, void* d_ws, size_t ws_size,
                              hipStream_t stream) {
  (void)in_sizes; (void)n_in; (void)out_size; (void)ws_size;
  const float* x      = (const float*)d_in[0];
  const float* xhat   = (const float*)d_in[1];
  const float* u      = (const float*)d_in[2];
  const float* m      = (const float*)d_in[3];
  const float* d      = (const float*)d_in[4];
  const float* W_td   = (const float*)d_in[6];
  const float* b_td   = (const float*)d_in[7];
  const float* W_hist = (const float*)d_in[8];
  const float* b_hist = (const float*)d_in[9];
  const float* W_v    = (const float*)d_in[10];
  const float* b_v    = (const float*)d_in[11];
  const float* W_r    = (const float*)d_in[12];
  const float* b_r    = (const float*)d_in[13];
  const float* W_u    = (const float*)d_in[14];
  const float* b_u    = (const float*)d_in[15];
  const float* conv_w = (const float*)d_in[16];
  const float* conv_b = (const float*)d_in[17];
  const float* W_ih   = (const float*)d_in[18];
  const float* b_ih   = (const float*)d_in[19];
  const float* W_hh   = (const float*)d_in[20];
  const float* b_hh   = (const float*)d_in[21];
  const float* W_fc   = (const float*)d_in[22];
  const float* b_fc   = (const float*)d_in[23];
  float* out = (float*)d_out;
  u16* wsu = (u16*)d_ws;
  float* msum = (float*)d_ws;
  const float* lossp = (const float*)((char*)d_ws + WS_LOSSP);

  hipLaunchKernelGGL(k0_pack, dim3(148), dim3(256), 0, stream,
                     W_td, W_u, W_v, W_r, W_hist, W_ih, msum, wsu);
  hipLaunchKernelGGL(k0b_pack8, dim3(144), dim3(256), 0, stream,
                     W_ih, W_hh, (u8*)d_ws);
  hipLaunchKernelGGL(k2_pre, dim3(1600), dim3(256), 0, stream,
                     x, xhat, u, m, d, b_td, b_u, b_v, b_r, b_ih, msum, out, wsu);
  hipLaunchKernelGGL(k_seq, dim3(32), dim3(512), 0, stream,
                     x, m, b_hist, b_hh, conv_w, conv_b, W_fc, b_fc, msum, out, wsu);
  hipLaunchKernelGGL(k3_loss, dim3(1), dim3(64), 0, stream, lossp, out);
}

// Round 4
// 1673.577 us; speedup vs baseline: 2.7462x; 1.0509x over previous
//
#include <hip/hip_runtime.h>

typedef unsigned short u16;
typedef unsigned int   u32;
typedef unsigned char  u8;
typedef unsigned long long u64;
typedef long i64;
typedef __attribute__((ext_vector_type(8))) short s16x8;
typedef __attribute__((ext_vector_type(4))) float f32x4;
typedef __attribute__((ext_vector_type(4), aligned(4))) float f32x4u;

#define DEV static __device__ __forceinline__

constexpr int B_ = 512, T_ = 200, V_ = 99, H_ = 256;
constexpr int TV_ = T_ * V_;

// d_out f32 element offsets: (x_imp, y_out, y_score, x_loss, xus, xrs)
constexpr long long XIMP_O = 0;
constexpr long long YOUT_O = 10137600;
constexpr long long YSC_O  = 10138112;
constexpr long long LOSS_O = 10138624;
constexpr long long XUS_O  = 10138625;
constexpr long long XRS_O  = 20276225;

// workspace byte offsets
constexpr long long WS_MSUM  = 0;                               // 200 f32
constexpr long long WS_GAMMA = 1024;                            // [T][B][H] bf16
constexpr long long WS_XRPRE = WS_GAMMA + 2ll * T_ * B_ * H_;   // [T][B][V] bf16
constexpr long long WS_GIPRE = WS_XRPRE + 2ll * T_ * B_ * V_;   // [T][32][48][64][4] bf16 (C-frag layout)
constexpr long long WS_WTD   = WS_GIPRE + 2ll * T_ * 32 * 48 * 256;
constexpr long long WS_WU    = WS_WTD   + 64ll  * 1024;
constexpr long long WS_WV    = WS_WU    + 28ll  * 1024;
constexpr long long WS_WR    = WS_WV    + 28ll  * 1024;
constexpr long long WS_WHIST = WS_WR    + 28ll  * 1024;
constexpr long long WS_WIHX  = WS_WHIST + 56ll  * 1024;
constexpr long long WS_WIHM  = WS_WIHX  + 192ll * 1024;
constexpr long long WS_WHH   = WS_WIHM  + 192ll * 1024;         // 384KB region for fp8 packs
constexpr long long WS_LOSSP = WS_WHH   + 384ll * 1024;         // 32 f32
// fp8 packs inside the WS_WHH region:
constexpr long long WS_WIHX8  = WS_WHH;            // 192 frags * 512B = 96KB
constexpr long long WS_WHH8   = WS_WHH + 98304;    // 384 frags = 192KB
constexpr long long WS_WHIST8 = WS_WHH + 294912;   // 56 frags = 28KB
constexpr long long WS_WR8    = WS_WHH + 323584;   // 28 frags = 14KB

DEV u16 cvt_bf16(float f) {
  union { float f; u32 u; } v; v.f = f;
  u32 u = v.u;
  return (u16)((u + 0x7fffu + ((u >> 16) & 1u)) >> 16);
}
DEV float cvt_f32(u16 h) {
  union { u32 u; float f; } v; v.u = ((u32)h) << 16;
  return v.f;
}
// OCP e4m3fn encoder (RNE) - pack kernels only (host-side precision path)
DEV u32 enc_e4m3(float f) {
  union { float f; u32 u; } v; v.f = f;
  u32 sign = (v.u >> 24) & 0x80u;
  v.u &= 0x7fffffffu;
  float a = fminf(v.f, 448.f);
  if (a < 0.015625f) {
    int mq = (int)rintf(a * 512.f);
    return sign | (u32)mq;
  }
  union { float f; u32 u; } w; w.f = a;
  u32 lsb = (w.u >> 20) & 1u;
  u32 r = w.u + 0x7FFFFu + lsb;
  u32 E = ((r >> 23) & 0xffu) - 120u;
  u32 M = (r >> 20) & 7u;
  if (E >= 16u) { E = 15u; M = 6u; }
  return sign | (E << 3) | M;
}
// HW packed converters (gfx950)
DEV u32 cvtfp8(float a) {
  u32 r;
  asm("v_cvt_pk_fp8_f32 %0, %1, %2" : "=v"(r) : "v"(a), "v"(a));
  return r;  // low byte = fp8(a)
}
DEV u32 pkbf(float a, float b) {
  u32 r;
  asm("v_cvt_pk_bf16_f32 %0, %1, %2" : "=v"(r) : "v"(a), "v"(b));
  return r;
}
DEV s16x8 mk8(f32x4 lo, f32x4 hi) {
  union { u32 q[4]; s16x8 v; } u;
  u.q[0] = pkbf(lo[0], lo[1]); u.q[1] = pkbf(lo[2], lo[3]);
  u.q[2] = pkbf(hi[0], hi[1]); u.q[3] = pkbf(hi[2], hi[3]);
  return u.v;
}
DEV f32x4 l4(const float* p) { return (f32x4)(*(const f32x4u*)p); }
DEV f32x4 mfma16(s16x8 a, s16x8 b, f32x4 c) {
  return __builtin_amdgcn_mfma_f32_16x16x32_bf16(a, b, c, 0, 0, 0);
}
DEV f32x4 mfma8(i64 a, i64 b, f32x4 c) {
  return __builtin_amdgcn_mfma_f32_16x16x32_fp8_fp8(a, b, c, 0, 0, 0);
}
// B-fragment from packed global bf16 weights
DEV s16x8 ldB(const u16* w, int frag, int lane) {
  return *reinterpret_cast<const s16x8*>(w + ((long long)frag * 64 + lane) * 8);
}
DEV f32x4 unpack_u64(u64 v) {
  return (f32x4){cvt_f32((u16)(v & 0xffffu)), cvt_f32((u16)((v >> 16) & 0xffffu)),
                 cvt_f32((u16)((v >> 32) & 0xffffu)), cvt_f32((u16)((v >> 48) & 0xffffu))};
}
DEV float sigm(float v) { return 1.f / (1.f + __expf(-v)); }
DEV float tanhx(float v) {
  float e = __expf(-2.f * fabsf(v));
  float t = (1.f - e) / (1.f + e);
  return v < 0.f ? -t : t;
}

// ---------------- K0: pack weights to bf16 MFMA-B fragment layout; zero msum ----------------
__global__ __launch_bounds__(256) void k0_pack(
    const float* __restrict__ W_td, const float* __restrict__ W_u, const float* __restrict__ W_v,
    const float* __restrict__ W_r, const float* __restrict__ W_hist, const float* __restrict__ W_ih,
    float* __restrict__ msum, u16* __restrict__ wsu) {
  if (blockIdx.x == 147) {
    if (threadIdx.x < T_) msum[threadIdx.x] = 0.f;
    return;
  }
  int frag = blockIdx.x * 4 + (threadIdx.x >> 6);
  int lane = threadIdx.x & 63;
  const float* src; long long off; int KC, koff, kmax, nmax, stride, diag = 0, f;
  if (frag < 64)       { f = frag;       src = W_td;   off = WS_WTD;   KC = 4; stride = 99;  koff = 0;  kmax = 99;  nmax = 256; }
  else if (frag < 92)  { f = frag - 64;  src = W_u;    off = WS_WU;    KC = 4; stride = 99;  koff = 0;  kmax = 99;  nmax = 99;  }
  else if (frag < 120) { f = frag - 92;  src = W_v;    off = WS_WV;    KC = 4; stride = 99;  koff = 0;  kmax = 99;  nmax = 99;  diag = 1; }
  else if (frag < 148) { f = frag - 120; src = W_r;    off = WS_WR;    KC = 4; stride = 99;  koff = 0;  kmax = 99;  nmax = 99;  diag = 1; }
  else if (frag < 204) { f = frag - 148; src = W_hist; off = WS_WHIST; KC = 8; stride = 256; koff = 0;  kmax = 256; nmax = 99;  }
  else if (frag < 396) { f = frag - 204; src = W_ih;   off = WS_WIHX;  KC = 4; stride = 198; koff = 0;  kmax = 99;  nmax = 768; }
  else if (frag < 588) { f = frag - 396; src = W_ih;   off = WS_WIHM;  KC = 4; stride = 198; koff = 99; kmax = 99;  nmax = 768; }
  else return;
  int nt = f / KC, kc = f % KC;
  int n = nt * 16 + (lane & 15);
  u16* dst = wsu + off / 2 + ((long long)f * 64 + lane) * 8;
#pragma unroll
  for (int j = 0; j < 8; j++) {
    int k = kc * 32 + ((lane >> 4) << 3) + j;
    float v = 0.f;
    if (k < kmax && n < nmax && !(diag && k == n)) v = src[(long long)n * stride + koff + k];
    dst[j] = cvt_bf16(v);
  }
}

// ---------------- K0b: pack W_ihx / W_hh / W_hist / W_r to fp8 e4m3 B-fragments (x16) ----------------
__global__ __launch_bounds__(256) void k0b_pack8(
    const float* __restrict__ W_ih, const float* __restrict__ W_hh,
    const float* __restrict__ W_hist, const float* __restrict__ W_r, u8* __restrict__ ws8) {
  int frag = blockIdx.x * 4 + (threadIdx.x >> 6);
  int lane = threadIdx.x & 63;
  const float* src; long long off; int KC, kmax, nmax, stride, diag = 0, f;
  if (frag < 192)      { f = frag;       src = W_ih;   off = WS_WIHX8;  KC = 4; stride = 198; kmax = 99;  nmax = 768; }
  else if (frag < 576) { f = frag - 192; src = W_hh;   off = WS_WHH8;   KC = 8; stride = 256; kmax = 256; nmax = 768; }
  else if (frag < 632) { f = frag - 576; src = W_hist; off = WS_WHIST8; KC = 8; stride = 256; kmax = 256; nmax = 99;  }
  else if (frag < 660) { f = frag - 632; src = W_r;    off = WS_WR8;    KC = 4; stride = 99;  kmax = 99;  nmax = 99;  diag = 1; }
  else return;
  int nt = f / KC, kc = f % KC;
  int n = nt * 16 + (lane & 15);
  u64 r = 0;
#pragma unroll
  for (int j = 0; j < 8; j++) {
    int k = kc * 32 + ((lane >> 4) << 3) + j;
    float v = 0.f;
    if (k < kmax && n < nmax && !(diag && k == n)) v = src[(long long)n * stride + k] * 16.f;
    r |= (u64)enc_e4m3(v) << (8 * j);
  }
  *reinterpret_cast<u64*>(ws8 + off + ((long long)f * 64 + lane) * 8) = r;
}

// ---------------- K2: parallel precompute (direct register gather, no LDS) ----------------
// grid 1600: one wave per (batch-chunk bc, t)
__global__ __launch_bounds__(256) void k2_pre(
    const float* __restrict__ x, const float* __restrict__ xh, const float* __restrict__ uu,
    const float* __restrict__ m, const float* __restrict__ dd,
    const float* __restrict__ b_td, const float* __restrict__ b_u, const float* __restrict__ b_v,
    const float* __restrict__ b_r, const float* __restrict__ b_ih,
    float* __restrict__ msum, float* __restrict__ out, u16* __restrict__ wsu) {
  const int tid = threadIdx.x, w = tid >> 6, lane = tid & 63;
  const int bc = blockIdx.x & 31, tg = blockIdx.x >> 5;
  const int t = tg * 4 + w;
  const int b0 = bc * 16;
  const int cl = lane & 15, rq = (lane >> 4) << 2, kr8 = (lane >> 4) << 3;
  const long long gb = (long long)(b0 + cl) * TV_ + (long long)t * V_;
  const u16* wtd  = wsu + WS_WTD / 2;
  const u16* wu   = wsu + WS_WU / 2;
  const u16* wv   = wsu + WS_WV / 2;
  const u16* wr   = wsu + WS_WR / 2;
  const u16* wihx = wsu + WS_WIHX / 2;
  const u16* wihm = wsu + WS_WIHM / 2;
  u16* gam = wsu + WS_GAMMA / 2;
  u16* xrp = wsu + WS_XRPRE / 2;
  u16* gip = wsu + WS_GIPRE / 2;
  const f32x4 z4 = {0.f, 0.f, 0.f, 0.f};

  // ---- gamma (uses fd only; fd freed after) ----
  {
    s16x8 fd[4];
#pragma unroll
    for (int kc = 0; kc < 3; kc++) {
      int k0 = kc * 32 + kr8;
      fd[kc] = mk8(l4(dd + gb + k0), l4(dd + gb + k0 + 4));
    }
    {
      f32x4 a = z4;
      if (kr8 == 0) { a[0] = dd[gb + 96]; a[1] = dd[gb + 97]; a[2] = dd[gb + 98]; }
      fd[3] = mk8(a, z4);
    }
    for (int nt = 0; nt < 16; nt++) {
      int col = nt * 16 + cl;
      float bt = b_td[col];
      f32x4 a = {bt, bt, bt, bt};
#pragma unroll
      for (int kc = 0; kc < 4; kc++) a = mfma16(fd[kc], ldB(wtd, nt * 4 + kc, lane), a);
#pragma unroll
      for (int j = 0; j < 4; j++) {
        int b = b0 + rq + j;
        gam[((long long)t * B_ + b) * H_ + col] = cvt_bf16(__expf(-fmaxf(a[j], 0.f)));
      }
    }
  }

  // ---- build fu, fxb, fmx, fm from one gather pass ----
  s16x8 fu[4], fxb[4], fmx[4], fm[4];
  float mpart = 0.f;
#pragma unroll
  for (int kc = 0; kc < 3; kc++) {
    int k0 = kc * 32 + kr8;
    f32x4 u0 = l4(uu + gb + k0), u1 = l4(uu + gb + k0 + 4);
    f32x4 m0 = l4(m + gb + k0),  m1 = l4(m + gb + k0 + 4);
    f32x4 x0 = l4(x + gb + k0),  x1 = l4(x + gb + k0 + 4);
    f32x4 h0 = l4(xh + gb + k0), h1 = l4(xh + gb + k0 + 4);
    fu[kc]  = mk8(u0, u1);
    fm[kc]  = mk8(m0, m1);
    fmx[kc] = mk8(m0 * x0, m1 * x1);
    fxb[kc] = mk8(h0 + m0 * (x0 - h0), h1 + m1 * (x1 - h1));
    mpart += m0[0] + m0[1] + m0[2] + m0[3] + m1[0] + m1[1] + m1[2] + m1[3];
  }
  {
    f32x4 u0 = z4, m0 = z4, x0 = z4, h0 = z4;
    if (kr8 == 0) {
#pragma unroll
      for (int e = 0; e < 3; e++) {
        u0[e] = uu[gb + 96 + e]; m0[e] = m[gb + 96 + e];
        x0[e] = x[gb + 96 + e];  h0[e] = xh[gb + 96 + e];
      }
    }
    fu[3]  = mk8(u0, z4);
    fm[3]  = mk8(m0, z4);
    fmx[3] = mk8(m0 * x0, z4);
    fxb[3] = mk8(h0 + m0 * (x0 - h0), z4);
    mpart += m0[0] + m0[1] + m0[2];
  }
  {
    float mp = mpart;
#pragma unroll
    for (int s = 32; s; s >>= 1) mp += __shfl_xor(mp, s);
    if (lane == 0) atomicAdd(&msum[t], mp);
  }

  // ---- V-wide GEMMs: unc / xu / xr_pre ----
  for (int nt = 0; nt < 7; nt++) {
    int col = nt * 16 + cl;
    float bu_ = 0.f, bv_ = 0.f, br_ = 0.f;
    if (col < V_) { bu_ = b_u[col]; bv_ = b_v[col]; br_ = b_r[col]; }
    f32x4 au = {bu_, bu_, bu_, bu_}, av = {bv_, bv_, bv_, bv_}, ar = {br_, br_, br_, br_};
#pragma unroll
    for (int kc = 0; kc < 4; kc++) {
      au = mfma16(fu[kc],  ldB(wu, nt * 4 + kc, lane), au);
      av = mfma16(fxb[kc], ldB(wv, nt * 4 + kc, lane), av);
      ar = mfma16(fmx[kc], ldB(wr, nt * 4 + kc, lane), ar);
    }
    if (col < V_) {
#pragma unroll
      for (int j = 0; j < 4; j++) {
        int b = b0 + rq + j;
        float unc = __expf(-fmaxf(au[j], 0.f));
        out[XUS_O + (long long)b * TV_ + (long long)t * V_ + col] = av[j] * unc;
        xrp[((long long)t * B_ + b) * V_ + col] = cvt_bf16(ar[j]);
      }
    }
  }
  // ---- gi_pre (C-fragment layout) ----
  for (int nt = 0; nt < 48; nt++) {
    int col = nt * 16 + cl;
    float bi = b_ih[col];
    f32x4 a = {bi, bi, bi, bi};
#pragma unroll
    for (int kc = 0; kc < 4; kc++) {
      a = mfma16(fmx[kc], ldB(wihx, nt * 4 + kc, lane), a);
      a = mfma16(fm[kc],  ldB(wihm, nt * 4 + kc, lane), a);
    }
    u32 p0 = pkbf(a[0], a[1]);
    u32 p1 = pkbf(a[2], a[3]);
    u32* gp = reinterpret_cast<u32*>(gip + (((long long)t * 32 + bc) * 48 + nt) * 256 + (long long)lane * 4);
    gp[0] = p0; gp[1] = p1;
  }
}

// ---------------- K_SEQ: persistent scan; 32 WGs x 1024 threads (16 waves, 4/SIMD) ----------------
// Per wave: one 16-col gate-triple. whh(z,n)+wihx fp8 in regs (56 VGPR);
// whh(r), whist, wr fp8 in LDS. All activations fp8(x8), weights fp8(x16), acc/128.
__global__ void __attribute__((amdgpu_flat_work_group_size(1024, 1024), amdgpu_waves_per_eu(4, 4)))
k_seq(
    const float* __restrict__ x, const float* __restrict__ m,
    const float* __restrict__ b_hist, const float* __restrict__ b_hh,
    const float* __restrict__ conv_w, const float* __restrict__ conv_b,
    const float* __restrict__ W_fc, const float* __restrict__ b_fc,
    const float* __restrict__ msum, float* out, u16* wsu) {
  __shared__ __align__(16) u8 hp8_s[16 * 272];    // fp8 hp (row stride 272)
  __shared__ __align__(16) u8 e8_s[16 * 144];     // fp8 e
  __shared__ __align__(16) u8 g8_s[16 * 144];     // fp8 g
  __shared__ __align__(16) u8 whhR_l[65536];      // r-gate whh fp8 (16 tiles x 8 kc)
  __shared__ __align__(16) u8 whist8_l[28672];    // whist fp8 (7 x 8)
  __shared__ __align__(16) u8 wr8_l[14336];       // wr fp8 (7 x 4)
  __shared__ __align__(16) float hf_s[16][260];   // final h for epilogue
  __shared__ float red_s[1024];

  const int tid = threadIdx.x, wv = tid >> 6, lane = tid & 63;
  const int cl = lane & 15, rq = (lane >> 4) << 2, kr8 = (lane >> 4) << 3;
  const int b0 = blockIdx.x * 16;
  const u8* ws8 = reinterpret_cast<const u8*>(wsu);

  // --- one-time LDS init ---
  for (int i = tid; i < 1088; i += 1024) reinterpret_cast<u32*>(hp8_s)[i] = 0;
  for (int i = tid; i < 576; i += 1024) { reinterpret_cast<u32*>(e8_s)[i] = 0; reinterpret_cast<u32*>(g8_s)[i] = 0; }
  {
    const u32* s0 = reinterpret_cast<const u32*>(ws8 + WS_WHH8);
    u32* d0 = reinterpret_cast<u32*>(whhR_l);
    for (int i = tid; i < 16384; i += 1024) d0[i] = s0[i];
    const u32* s1 = reinterpret_cast<const u32*>(ws8 + WS_WHIST8);
    u32* d1 = reinterpret_cast<u32*>(whist8_l);
    for (int i = tid; i < 7168; i += 1024) d1[i] = s1[i];
    const u32* s2 = reinterpret_cast<const u32*>(ws8 + WS_WR8);
    u32* d2 = reinterpret_cast<u32*>(wr8_l);
    for (int i = tid; i < 3584; i += 1024) d2[i] = s2[i];
  }

  // --- resident fp8 weights: wihx (3 gates) + whh z,n ---
  const u64* wx8 = reinterpret_cast<const u64*>(ws8 + WS_WIHX8);
  const u64* wh8 = reinterpret_cast<const u64*>(ws8 + WS_WHH8);
  i64 wihx_r[3][4];
  i64 whhZ[8], whhN[8];
#pragma unroll
  for (int gg = 0; gg < 3; gg++)
#pragma unroll
    for (int kc = 0; kc < 4; kc++)
      wihx_r[gg][kc] = (i64)wx8[(long long)((gg * 16 + wv) * 4 + kc) * 64 + lane];
#pragma unroll
  for (int kc = 0; kc < 8; kc++) {
    whhZ[kc] = (i64)wh8[(long long)((16 + wv) * 8 + kc) * 64 + lane];
    whhN[kc] = (i64)wh8[(long long)((32 + wv) * 8 + kc) * 64 + lane];
  }

  const int col = wv * 16 + cl;
  const float bhh0 = b_hh[col], bhh1 = b_hh[256 + col], bhh2 = b_hh[512 + col];
  const bool vwave = (wv < 7);
  const bool vact = vwave && (col < V_);
  const float bh = vact ? b_hist[col] : 0.f;
  const float cw0 = conv_w[0], cw1 = conv_w[1], cb = conv_b[0];
  const u16* gamp = wsu + WS_GAMMA / 2;
  const u16* xrpp = wsu + WS_XRPRE / 2;
  const u64* gipb = reinterpret_cast<const u64*>(wsu + WS_GIPRE / 2);
  const u64* gq0 = gipb + ((long long)blockIdx.x * 48 + wv) * 64 + lane;
  const u64* gq1 = gq0 + 16 * 64;
  const u64* gq2 = gq0 + 32 * 64;
  u32 gaidx = (u32)(B_ + b0 + rq) * H_ + col;
  u32 gidx = (u32)(b0 + rq) * TV_ + col;
  u32 xridx = (u32)(b0 + rq) * V_ + col;
  const float* xup = out + XUS_O;
  float* outi = out + XIMP_O;
  float* outr = out + XRS_O;
  float hpr[4] = {0.f, 0.f, 0.f, 0.f};
  float loss_acc = 0.f;
  constexpr float inv128 = 1.f / 128.f;
  const f32x4 z4 = {0.f, 0.f, 0.f, 0.f};
  __syncthreads();

  for (int t = 0; t < T_; t++) {
    // ---- step-top prefetch ----
    const u64 gi0 = *gq0, gi1 = *gq1, gi2 = *gq2;
    gq0 += 98304; gq1 += 98304; gq2 += 98304;
    u16 ga0 = 0, ga1 = 0, ga2 = 0, ga3 = 0;
    if (t + 1 < T_) {
      ga0 = gamp[gaidx]; ga1 = gamp[gaidx + H_];
      ga2 = gamp[gaidx + 2 * H_]; ga3 = gamp[gaidx + 3 * H_];
      gaidx += B_ * H_;
    }
    float xj[4] = {0.f, 0.f, 0.f, 0.f}, mj[4] = {0.f, 0.f, 0.f, 0.f}, xuv[4] = {0.f, 0.f, 0.f, 0.f};
    u16 xrv16[4] = {0, 0, 0, 0};
    if (vact) {
#pragma unroll
      for (int j = 0; j < 4; j++) {
        const u32 gj = gidx + j * TV_;
        xj[j] = x[gj]; mj[j] = m[gj]; xuv[j] = xup[gj];
        xrv16[j] = xrpp[xridx + j * V_];
      }
    }
    const float msv = msum[t];

    // ---- P1: gh chains (r from LDS, z/n resident) + x_h (whist fp8) ----
    f32x4 accR = z4, accZ = z4, accNh = z4;
#pragma unroll
    for (int kc = 0; kc < 8; kc++) {
      const i64 a = *reinterpret_cast<const i64*>(&hp8_s[cl * 272 + kc * 32 + kr8]);
      const i64 br = *reinterpret_cast<const i64*>(&whhR_l[(wv * 8 + kc) * 512 + lane * 8]);
      accR  = mfma8(a, br, accR);
      accZ  = mfma8(a, whhZ[kc], accZ);
      accNh = mfma8(a, whhN[kc], accNh);
    }
    if (vwave) {
      f32x4 accXh = z4;
#pragma unroll
      for (int kc = 0; kc < 8; kc++) {
        const i64 a = *reinterpret_cast<const i64*>(&hp8_s[cl * 272 + kc * 32 + kr8]);
        const i64 bw = *reinterpret_cast<const i64*>(&whist8_l[(wv * 8 + kc) * 512 + lane * 8]);
        accXh = mfma8(a, bw, accXh);
      }
      if (vact) {
#pragma unroll
        for (int j = 0; j < 4; j++) {
          const float ev = (1.f - mj[j]) * (accXh[j] * inv128 + bh);
          e8_s[(rq + j) * 144 + col] = (u8)cvtfp8(ev * 8.f);
        }
      }
    }
    __syncthreads();

    // ---- P2: xr, x_comb, loss, x_imp, xrs, g8 ----
    if (vwave) {
      f32x4 acc = z4;
#pragma unroll
      for (int kc = 0; kc < 4; kc++) {
        const i64 a = *reinterpret_cast<const i64*>(&e8_s[cl * 144 + kc * 32 + kr8]);
        const i64 b = *reinterpret_cast<const i64*>(&wr8_l[(wv * 4 + kc) * 512 + lane * 8]);
        acc = mfma8(a, b, acc);
      }
      if (vact) {
        const float inv_ms = 1.f / (msv + 1e-5f);
        float ls = 0.f;
#pragma unroll
        for (int j = 0; j < 4; j++) {
          const float xrv = acc[j] * inv128 + cvt_f32(xrv16[j]);
          const float xc = cw0 * xuv[j] + cw1 * xrv + cb;
          ls += fabsf(xj[j] - xc) * mj[j];
          const u32 gj = gidx + j * TV_;
          outi[gj] = mj[j] * xj[j] + (1.f - mj[j]) * xc;
          outr[gj] = xrv;
          g8_s[(rq + j) * 144 + col] = (u8)cvtfp8((1.f - mj[j]) * xc * 8.f);
        }
        loss_acc += ls * inv_ms;
      }
    }
    gidx += V_; xridx += B_ * V_;
    __syncthreads();

    // ---- P3: gi corrections + GRU update (+ fused gamma[t+1]) ----
    f32x4 accNx = z4;
#pragma unroll
    for (int kc = 0; kc < 4; kc++) {
      const i64 a = *reinterpret_cast<const i64*>(&g8_s[cl * 144 + kc * 32 + kr8]);
      accR  = mfma8(a, wihx_r[0][kc], accR);
      accZ  = mfma8(a, wihx_r[1][kc], accZ);
      accNx = mfma8(a, wihx_r[2][kc], accNx);
    }
    const f32x4 gr = unpack_u64(gi0);
    const f32x4 gz = unpack_u64(gi1);
    const f32x4 gn = unpack_u64(gi2);
    if (t + 1 < T_) {
      const u16 gaa[4] = {ga0, ga1, ga2, ga3};
#pragma unroll
      for (int j = 0; j < 4; j++) {
        const float rr = sigm(gr[j] + accR[j] * inv128 + bhh0);
        const float zz = sigm(gz[j] + accZ[j] * inv128 + bhh1);
        const float ghn = accNh[j] * inv128 + bhh2;
        const float nn = tanhx(gn[j] + accNx[j] * inv128 + rr * ghn);
        const float hn = (1.f - zz) * nn + zz * hpr[j];
        const float hpnew = hn * cvt_f32(gaa[j]);
        hpr[j] = hpnew;
        hp8_s[(rq + j) * 272 + col] = (u8)cvtfp8(hpnew * 8.f);
      }
    } else {
#pragma unroll
      for (int j = 0; j < 4; j++) {
        const float rr = sigm(gr[j] + accR[j] * inv128 + bhh0);
        const float zz = sigm(gz[j] + accZ[j] * inv128 + bhh1);
        const float ghn = accNh[j] * inv128 + bhh2;
        const float nn = tanhx(gn[j] + accNx[j] * inv128 + rr * ghn);
        hf_s[rq + j][col] = (1.f - zz) * nn + zz * hpr[j];
      }
    }
    __syncthreads();
  }

  // ---- epilogue: y_out / y_score ----
  if (tid < 16) {
    float acc = 0.f;
    for (int k = 0; k < H_; k++) acc += hf_s[tid][k] * W_fc[k];
    const float yv = acc + b_fc[0];
    out[YOUT_O + b0 + tid] = yv;
    out[YSC_O + b0 + tid] = 1.f / (1.f + __expf(-yv));
  }
  red_s[tid] = loss_acc;
  __syncthreads();
  for (int s = 512; s; s >>= 1) {
    if (tid < s) red_s[tid] += red_s[tid + s];
    __syncthreads();
  }
  if (tid == 0) {
    float* lp = reinterpret_cast<float*>(reinterpret_cast<char*>(wsu) + WS_LOSSP);
    lp[blockIdx.x] = red_s[0];
  }
}

// ---------------- K3: deterministic loss reduction ----------------
__global__ void k3_loss(const float* __restrict__ lossp, float* __restrict__ out) {
  if (threadIdx.x == 0) {
    float s = 0.f;
    for (int i = 0; i < 32; i++) s += lossp[i];
    out[LOSS_O] = s;
  }
}

extern "C" void kernel_launch(void* const* d_in, const int* in_sizes, int n_in,
                              void* d_out, int out_size, void* d_ws, size_t ws_size,
                              hipStream_t stream) {
  (void)in_sizes; (void)n_in; (void)out_size; (void)ws_size;
  const float* x      = (const float*)d_in[0];
  const float* xhat   = (const float*)d_in[1];
  const float* u      = (const float*)d_in[2];
  const float* m      = (const float*)d_in[3];
  const float* d      = (const float*)d_in[4];
  const float* W_td   = (const float*)d_in[6];
  const float* b_td   = (const float*)d_in[7];
  const float* W_hist = (const float*)d_in[8];
  const float* b_hist = (const float*)d_in[9];
  const float* W_v    = (const float*)d_in[10];
  const float* b_v    = (const float*)d_in[11];
  const float* W_r    = (const float*)d_in[12];
  const float* b_r    = (const float*)d_in[13];
  const float* W_u    = (const float*)d_in[14];
  const float* b_u    = (const float*)d_in[15];
  const float* conv_w = (const float*)d_in[16];
  const float* conv_b = (const float*)d_in[17];
  const float* W_ih   = (const float*)d_in[18];
  const float* b_ih   = (const float*)d_in[19];
  const float* W_hh   = (const float*)d_in[20];
  const float* b_hh   = (const float*)d_in[21];
  const float* W_fc   = (const float*)d_in[22];
  const float* b_fc   = (const float*)d_in[23];
  float* out = (float*)d_out;
  u16* wsu = (u16*)d_ws;
  float* msum = (float*)d_ws;
  const float* lossp = (const float*)((char*)d_ws + WS_LOSSP);

  hipLaunchKernelGGL(k0_pack, dim3(148), dim3(256), 0, stream,
                     W_td, W_u, W_v, W_r, W_hist, W_ih, msum, wsu);
  hipLaunchKernelGGL(k0b_pack8, dim3(165), dim3(256), 0, stream,
                     W_ih, W_hh, W_hist, W_r, (u8*)d_ws);
  hipLaunchKernelGGL(k2_pre, dim3(1600), dim3(256), 0, stream,
                     x, xhat, u, m, d, b_td, b_u, b_v, b_r, b_ih, msum, out, wsu);
  hipLaunchKernelGGL(k_seq, dim3(32), dim3(1024), 0, stream,
                     x, m, b_hist, b_hh, conv_w, conv_b, W_fc, b_fc, msum, out, wsu);
  hipLaunchKernelGGL(k3_loss, dim3(1), dim3(64), 0, stream, lossp, out);
}

// Round 5
// 1321.208 us; speedup vs baseline: 3.4787x; 1.2667x over previous
//
#include <hip/hip_runtime.h>

typedef unsigned short u16;
typedef unsigned int   u32;
typedef unsigned char  u8;
typedef unsigned long long u64;
typedef long i64;
typedef __attribute__((ext_vector_type(8))) short s16x8;
typedef __attribute__((ext_vector_type(4))) float f32x4;
typedef __attribute__((ext_vector_type(2))) float f32x2;
typedef __attribute__((ext_vector_type(4), aligned(4))) float f32x4u;

#define DEV static __device__ __forceinline__

constexpr int B_ = 512, T_ = 200, V_ = 99, H_ = 256;
constexpr int TV_ = T_ * V_;
constexpr u32 BH_ = B_ * H_;

// d_out f32 element offsets: (x_imp, y_out, y_score, x_loss, xus, xrs)
constexpr long long XIMP_O = 0;
constexpr long long YOUT_O = 10137600;
constexpr long long YSC_O  = 10138112;
constexpr long long LOSS_O = 10138624;
constexpr long long XUS_O  = 10138625;
constexpr long long XRS_O  = 20276225;

// ---- workspace byte offsets ----
constexpr long long WS_MSUM   = 0;                          // 200 f32
constexpr long long WS_GAMMA  = 1024;                       // [T][B][H] bf16 (52,428,800)
constexpr long long WS_XRPRE  = 52429824;                   // [T][B][99] bf16 (20,275,200)
constexpr long long WS_X16    = 72705024;                   // [T][B][100] bf16 (20,480,000)
constexpr long long WS_XUS16  = 93185024;                   // [T][B][99] bf16 (20,275,200)
constexpr long long WS_M8     = 113460224;                  // [T][B][104] u8  (10,649,600)
constexpr long long WS_GIM8   = 124109824;                  // [T][32][48][64][4] u8 (78,643,200)
constexpr long long WS_WTD    = 202753024;                  // bf16 packs
constexpr long long WS_WU     = WS_WTD + 65536;
constexpr long long WS_WV     = WS_WU + 28672;
constexpr long long WS_WRB    = WS_WV + 28672;
constexpr long long WS_WIHM_B = WS_WRB + 28672;             // 192 frags * 1024B
constexpr long long WS_F8     = WS_WIHM_B + 196608;         // fp8 packs
constexpr long long WS_WIHX8  = WS_F8;                      // 96KB
constexpr long long WS_WHH8   = WS_F8 + 98304;              // 192KB
constexpr long long WS_WHIST8 = WS_F8 + 294912;             // 28KB
constexpr long long WS_WR8    = WS_F8 + 323584;             // 14KB
constexpr long long WS_LOSSP  = WS_F8 + 337920;             // 64 f32

DEV u16 cvt_bf16(float f) {
  union { float f; u32 u; } v; v.f = f;
  u32 u = v.u;
  return (u16)((u + 0x7fffu + ((u >> 16) & 1u)) >> 16);
}
DEV float cvt_f32(u16 h) {
  union { u32 u; float f; } v; v.u = ((u32)h) << 16;
  return v.f;
}
// OCP e4m3fn encoder (RNE) - pack kernels only
DEV u32 enc_e4m3(float f) {
  union { float f; u32 u; } v; v.f = f;
  u32 sign = (v.u >> 24) & 0x80u;
  v.u &= 0x7fffffffu;
  float a = fminf(v.f, 448.f);
  if (a < 0.015625f) {
    int mq = (int)rintf(a * 512.f);
    return sign | (u32)mq;
  }
  union { float f; u32 u; } w; w.f = a;
  u32 lsb = (w.u >> 20) & 1u;
  u32 r = w.u + 0x7FFFFu + lsb;
  u32 E = ((r >> 23) & 0xffu) - 120u;
  u32 M = (r >> 20) & 7u;
  if (E >= 16u) { E = 15u; M = 6u; }
  return sign | (E << 3) | M;
}
// HW packed converters (gfx950)
DEV u32 cvtfp8(float a) {
  u32 r;
  asm("v_cvt_pk_fp8_f32 %0, %1, %2" : "=v"(r) : "v"(a), "v"(a));
  return r;  // low byte = fp8(a)
}
DEV u32 cvtfp8x2(float a, float b) {
  u32 r;
  asm("v_cvt_pk_fp8_f32 %0, %1, %2" : "=v"(r) : "v"(a), "v"(b));
  return r & 0xffffu;
}
DEV u32 pkbf(float a, float b) {
  u32 r;
  asm("v_cvt_pk_bf16_f32 %0, %1, %2" : "=v"(r) : "v"(a), "v"(b));
  return r;
}
#if __has_builtin(__builtin_amdgcn_cvt_pk_f32_fp8)
DEV f32x4 dec8x4(u32 w) {
  f32x2 lo = __builtin_amdgcn_cvt_pk_f32_fp8((int)w, false);
  f32x2 hi = __builtin_amdgcn_cvt_pk_f32_fp8((int)w, true);
  return (f32x4){lo[0], lo[1], hi[0], hi[1]};
}
#else
DEV float dec8(u32 b) {
  u32 e = (b >> 3) & 0xfu, mm = b & 7u, s = b >> 7;
  union { u32 u; float f; } v;
  v.u = (s << 31) | ((e + 120u) << 23) | (mm << 20);
  return e ? v.f : 0.f;
}
DEV f32x4 dec8x4(u32 w) {
  return (f32x4){dec8(w & 0xff), dec8((w >> 8) & 0xff), dec8((w >> 16) & 0xff), dec8(w >> 24)};
}
#endif
DEV s16x8 mk8(f32x4 lo, f32x4 hi) {
  union { u32 q[4]; s16x8 v; } u;
  u.q[0] = pkbf(lo[0], lo[1]); u.q[1] = pkbf(lo[2], lo[3]);
  u.q[2] = pkbf(hi[0], hi[1]); u.q[3] = pkbf(hi[2], hi[3]);
  return u.v;
}
DEV f32x4 l4(const float* p) { return (f32x4)(*(const f32x4u*)p); }
DEV f32x4 mfma16(s16x8 a, s16x8 b, f32x4 c) {
  return __builtin_amdgcn_mfma_f32_16x16x32_bf16(a, b, c, 0, 0, 0);
}
DEV f32x4 mfma8(i64 a, i64 b, f32x4 c) {
  return __builtin_amdgcn_mfma_f32_16x16x32_fp8_fp8(a, b, c, 0, 0, 0);
}
DEV s16x8 ldB(const u16* w, int frag, int lane) {
  return *reinterpret_cast<const s16x8*>(w + ((long long)frag * 64 + lane) * 8);
}
DEV float sigm(float v) { return 1.f / (1.f + __expf(-v)); }
DEV float tanhx(float v) {
  float e = __expf(-2.f * fabsf(v));
  float t = (1.f - e) / (1.f + e);
  return v < 0.f ? -t : t;
}

// ---------------- K0: pack bf16 MFMA-B fragments (k2's weights); zero msum ----------------
__global__ __launch_bounds__(256) void k0_pack(
    const float* __restrict__ W_td, const float* __restrict__ W_u, const float* __restrict__ W_v,
    const float* __restrict__ W_r, const float* __restrict__ W_ih,
    float* __restrict__ msum, u16* __restrict__ wsu) {
  if (blockIdx.x == 85) {
    if (threadIdx.x < T_) msum[threadIdx.x] = 0.f;
    return;
  }
  int frag = blockIdx.x * 4 + (threadIdx.x >> 6);
  int lane = threadIdx.x & 63;
  const float* src; long long off; int koff, kmax, nmax, stride, diag = 0, f;
  if (frag < 64)       { f = frag;       src = W_td; off = WS_WTD;    stride = 99;  koff = 0;  kmax = 99; nmax = 256; }
  else if (frag < 92)  { f = frag - 64;  src = W_u;  off = WS_WU;     stride = 99;  koff = 0;  kmax = 99; nmax = 99;  }
  else if (frag < 120) { f = frag - 92;  src = W_v;  off = WS_WV;     stride = 99;  koff = 0;  kmax = 99; nmax = 99;  diag = 1; }
  else if (frag < 148) { f = frag - 120; src = W_r;  off = WS_WRB;    stride = 99;  koff = 0;  kmax = 99; nmax = 99;  diag = 1; }
  else if (frag < 340) { f = frag - 148; src = W_ih; off = WS_WIHM_B; stride = 198; koff = 99; kmax = 99; nmax = 768; }
  else return;
  int nt = f / 4, kc = f % 4;
  int n = nt * 16 + (lane & 15);
  u16* dst = wsu + off / 2 + ((long long)f * 64 + lane) * 8;
#pragma unroll
  for (int j = 0; j < 8; j++) {
    int k = kc * 32 + ((lane >> 4) << 3) + j;
    float v = 0.f;
    if (k < kmax && n < nmax && !(diag && k == n)) v = src[(long long)n * stride + koff + k];
    dst[j] = cvt_bf16(v);
  }
}

// ---------------- K0b: pack W_ihx / W_hh / W_hist / W_r to fp8 e4m3 B-fragments (x16) ----------------
__global__ __launch_bounds__(256) void k0b_pack8(
    const float* __restrict__ W_ih, const float* __restrict__ W_hh,
    const float* __restrict__ W_hist, const float* __restrict__ W_r, u8* __restrict__ ws8) {
  int frag = blockIdx.x * 4 + (threadIdx.x >> 6);
  int lane = threadIdx.x & 63;
  const float* src; long long off; int KC, kmax, nmax, stride, diag = 0, f;
  if (frag < 192)      { f = frag;       src = W_ih;   off = WS_WIHX8;  KC = 4; stride = 198; kmax = 99;  nmax = 768; }
  else if (frag < 576) { f = frag - 192; src = W_hh;   off = WS_WHH8;   KC = 8; stride = 256; kmax = 256; nmax = 768; }
  else if (frag < 632) { f = frag - 576; src = W_hist; off = WS_WHIST8; KC = 8; stride = 256; kmax = 256; nmax = 99;  }
  else if (frag < 660) { f = frag - 632; src = W_r;    off = WS_WR8;    KC = 4; stride = 99;  kmax = 99;  nmax = 99;  diag = 1; }
  else return;
  int nt = f / KC, kc = f % KC;
  int n = nt * 16 + (lane & 15);
  u64 r = 0;
#pragma unroll
  for (int j = 0; j < 8; j++) {
    int k = kc * 32 + ((lane >> 4) << 3) + j;
    float v = 0.f;
    if (k < kmax && n < nmax && !(diag && k == n)) v = src[(long long)n * stride + k] * 16.f;
    r |= (u64)enc_e4m3(v) << (8 * j);
  }
  *reinterpret_cast<u64*>(ws8 + off + ((long long)f * 64 + lane) * 8) = r;
}

// ---------------- K2: parallel precompute ----------------
// grid 1600: one wave per (batch-chunk bc in [0,32), t)
__global__ __launch_bounds__(256) void k2_pre(
    const float* __restrict__ x, const float* __restrict__ xh, const float* __restrict__ uu,
    const float* __restrict__ m, const float* __restrict__ dd,
    const float* __restrict__ b_td, const float* __restrict__ b_u, const float* __restrict__ b_v,
    const float* __restrict__ b_r, const float* __restrict__ b_ih,
    float* __restrict__ msum, float* __restrict__ out, u16* __restrict__ wsu) {
  const int tid = threadIdx.x, w = tid >> 6, lane = tid & 63;
  const int bc = blockIdx.x & 31, tg = blockIdx.x >> 5;
  const int t = tg * 4 + w;
  const int b0 = bc * 16;
  const int cl = lane & 15, rq = (lane >> 4) << 2, kr8 = (lane >> 4) << 3;
  const long long gb = (long long)(b0 + cl) * TV_ + (long long)t * V_;
  u8* ws8 = reinterpret_cast<u8*>(wsu);
  const u16* wtd   = wsu + WS_WTD / 2;
  const u16* wu    = wsu + WS_WU / 2;
  const u16* wv    = wsu + WS_WV / 2;
  const u16* wrb   = wsu + WS_WRB / 2;
  const u16* wihmb = wsu + WS_WIHM_B / 2;
  u16* gam = wsu + WS_GAMMA / 2;
  u16* xrp = wsu + WS_XRPRE / 2;
  u16* x16p = wsu + WS_X16 / 2;
  u16* xu16p = wsu + WS_XUS16 / 2;
  u8* m8p = ws8 + WS_M8;
  u8* gim8p = ws8 + WS_GIM8;
  const f32x4 z4 = {0.f, 0.f, 0.f, 0.f};

  // ---- gamma ----
  {
    s16x8 fd[4];
#pragma unroll
    for (int kc = 0; kc < 3; kc++) {
      int k0 = kc * 32 + kr8;
      fd[kc] = mk8(l4(dd + gb + k0), l4(dd + gb + k0 + 4));
    }
    {
      f32x4 a = z4;
      if (kr8 == 0) { a[0] = dd[gb + 96]; a[1] = dd[gb + 97]; a[2] = dd[gb + 98]; }
      fd[3] = mk8(a, z4);
    }
    for (int nt = 0; nt < 16; nt++) {
      int col = nt * 16 + cl;
      float bt = b_td[col];
      f32x4 a = {bt, bt, bt, bt};
#pragma unroll
      for (int kc = 0; kc < 4; kc++) a = mfma16(fd[kc], ldB(wtd, nt * 4 + kc, lane), a);
#pragma unroll
      for (int j = 0; j < 4; j++) {
        int b = b0 + rq + j;
        gam[((long long)t * B_ + b) * H_ + col] = cvt_bf16(__expf(-fmaxf(a[j], 0.f)));
      }
    }
  }

  // ---- gather pass: build frags + emit x16 / m8 copies ----
  s16x8 fu[4], fxb[4], fmx[4], fm[4];
  float mpart = 0.f;
  const long long rowoff = (long long)t * B_ + (b0 + cl);
  u16* x16row = x16p + rowoff * 100;
  u8* m8row = m8p + rowoff * 104;
#pragma unroll
  for (int kc = 0; kc < 3; kc++) {
    int k0 = kc * 32 + kr8;
    f32x4 u0 = l4(uu + gb + k0), u1 = l4(uu + gb + k0 + 4);
    f32x4 m0 = l4(m + gb + k0),  m1 = l4(m + gb + k0 + 4);
    f32x4 x0 = l4(x + gb + k0),  x1 = l4(x + gb + k0 + 4);
    f32x4 h0 = l4(xh + gb + k0), h1 = l4(xh + gb + k0 + 4);
    fu[kc]  = mk8(u0, u1);
    fm[kc]  = mk8(m0, m1);
    fmx[kc] = mk8(m0 * x0, m1 * x1);
    fxb[kc] = mk8(h0 + m0 * (x0 - h0), h1 + m1 * (x1 - h1));
    mpart += m0[0] + m0[1] + m0[2] + m0[3] + m1[0] + m1[1] + m1[2] + m1[3];
    u64 xw0 = (u64)pkbf(x0[0], x0[1]) | ((u64)pkbf(x0[2], x0[3]) << 32);
    u64 xw1 = (u64)pkbf(x1[0], x1[1]) | ((u64)pkbf(x1[2], x1[3]) << 32);
    *reinterpret_cast<u64*>(x16row + k0) = xw0;
    *reinterpret_cast<u64*>(x16row + k0 + 4) = xw1;
    u64 mb = 0;
#pragma unroll
    for (int e = 0; e < 4; e++) {
      mb |= (m0[e] > 0.5f ? 0x50ull : 0ull) << (8 * e);
      mb |= (m1[e] > 0.5f ? 0x50ull : 0ull) << (32 + 8 * e);
    }
    *reinterpret_cast<u64*>(m8row + k0) = mb;
  }
  {
    f32x4 u0 = z4, m0 = z4, x0 = z4, h0 = z4;
    if (kr8 == 0) {
#pragma unroll
      for (int e = 0; e < 3; e++) {
        u0[e] = uu[gb + 96 + e]; m0[e] = m[gb + 96 + e];
        x0[e] = x[gb + 96 + e];  h0[e] = xh[gb + 96 + e];
      }
#pragma unroll
      for (int e = 0; e < 3; e++) {
        x16row[96 + e] = cvt_bf16(x0[e]);
        m8row[96 + e] = (m0[e] > 0.5f) ? 0x50 : 0;
      }
    }
    fu[3]  = mk8(u0, z4);
    fm[3]  = mk8(m0, z4);
    fmx[3] = mk8(m0 * x0, z4);
    fxb[3] = mk8(h0 + m0 * (x0 - h0), z4);
    mpart += m0[0] + m0[1] + m0[2];
  }
  {
    float mp = mpart;
#pragma unroll
    for (int s = 32; s; s >>= 1) mp += __shfl_xor(mp, s);
    if (lane == 0) atomicAdd(&msum[t], mp);
  }

  // ---- V-wide GEMMs: unc / xu / xr_pre ----
  for (int nt = 0; nt < 7; nt++) {
    int col = nt * 16 + cl;
    float bu_ = 0.f, bv_ = 0.f, br_ = 0.f;
    if (col < V_) { bu_ = b_u[col]; bv_ = b_v[col]; br_ = b_r[col]; }
    f32x4 au = {bu_, bu_, bu_, bu_}, av = {bv_, bv_, bv_, bv_}, ar = {br_, br_, br_, br_};
#pragma unroll
    for (int kc = 0; kc < 4; kc++) {
      au = mfma16(fu[kc],  ldB(wu, nt * 4 + kc, lane), au);
      av = mfma16(fxb[kc], ldB(wv, nt * 4 + kc, lane), av);
      ar = mfma16(fmx[kc], ldB(wrb, nt * 4 + kc, lane), ar);
    }
    if (col < V_) {
#pragma unroll
      for (int j = 0; j < 4; j++) {
        int b = b0 + rq + j;
        float unc = __expf(-fmaxf(au[j], 0.f));
        float xuv = av[j] * unc;
        out[XUS_O + (long long)b * TV_ + (long long)t * V_ + col] = xuv;
        xu16p[((long long)t * B_ + b) * V_ + col] = cvt_bf16(xuv);
        xrp[((long long)t * B_ + b) * V_ + col] = cvt_bf16(ar[j]);
      }
    }
  }
  // ---- gim8 = fp8( (b_ih + m @ W_ihm) * 64 ), C-frag layout ----
  for (int nt = 0; nt < 48; nt++) {
    int col = nt * 16 + cl;
    float bi = b_ih[col];
    f32x4 a = {bi, bi, bi, bi};
#pragma unroll
    for (int kc = 0; kc < 4; kc++) a = mfma16(fm[kc], ldB(wihmb, nt * 4 + kc, lane), a);
    u32 p = cvtfp8x2(a[0] * 64.f, a[1] * 64.f) | (cvtfp8x2(a[2] * 64.f, a[3] * 64.f) << 16);
    *reinterpret_cast<u32*>(gim8p + (((long long)t * 32 + bc) * 48 + nt) * 256 + (long long)lane * 4) = p;
  }
}

// ---------------- K_SEQ: persistent scan; 64 WGs x 8 batch rows x 1024 threads ----------------
__global__ void __attribute__((amdgpu_flat_work_group_size(1024, 1024), amdgpu_waves_per_eu(4, 4)))
k_seq(
    const float* __restrict__ b_hist, const float* __restrict__ b_hh,
    const float* __restrict__ conv_w, const float* __restrict__ conv_b,
    const float* __restrict__ W_fc, const float* __restrict__ b_fc,
    const float* __restrict__ msum, float* out, u16* wsu) {
  __shared__ __align__(16) u8 hp8_s[16 * 272];
  __shared__ __align__(16) u8 e8_s[16 * 144];
  __shared__ __align__(16) u8 xi8_s[16 * 144];
  __shared__ __align__(16) u8 whhR_l[65536];
  __shared__ __align__(16) u8 whist8_l[28672];
  __shared__ __align__(16) u8 wr8_l[14336];
  __shared__ __align__(16) float hf_s[8][260];
  __shared__ float red_s[1024];

  const int tid = threadIdx.x, wv = tid >> 6, lane = tid & 63;
  const int cl = lane & 15, rq = (lane >> 4) << 2, kr8 = (lane >> 4) << 3;
  const int b0 = blockIdx.x * 8;
  const int cc = blockIdx.x >> 1, half = blockIdx.x & 1;
  const u8* ws8 = reinterpret_cast<const u8*>(wsu);

  for (int i = tid; i < 1088; i += 1024) reinterpret_cast<u32*>(hp8_s)[i] = 0;
  for (int i = tid; i < 576; i += 1024) { reinterpret_cast<u32*>(e8_s)[i] = 0; reinterpret_cast<u32*>(xi8_s)[i] = 0; }
  {
    const u32* s0 = reinterpret_cast<const u32*>(ws8 + WS_WHH8);
    u32* d0 = reinterpret_cast<u32*>(whhR_l);
    for (int i = tid; i < 16384; i += 1024) d0[i] = s0[i];
    const u32* s1 = reinterpret_cast<const u32*>(ws8 + WS_WHIST8);
    u32* d1 = reinterpret_cast<u32*>(whist8_l);
    for (int i = tid; i < 7168; i += 1024) d1[i] = s1[i];
    const u32* s2 = reinterpret_cast<const u32*>(ws8 + WS_WR8);
    u32* d2 = reinterpret_cast<u32*>(wr8_l);
    for (int i = tid; i < 3584; i += 1024) d2[i] = s2[i];
  }

  // resident fp8 weights: wihx (3 gates) + whh z,n  (56 regs)
  const u64* wx8 = reinterpret_cast<const u64*>(ws8 + WS_WIHX8);
  const u64* wh8 = reinterpret_cast<const u64*>(ws8 + WS_WHH8);
  i64 wihx_r[3][4];
  i64 whhZ[8], whhN[8];
#pragma unroll
  for (int gg = 0; gg < 3; gg++)
#pragma unroll
    for (int kc = 0; kc < 4; kc++)
      wihx_r[gg][kc] = (i64)wx8[(long long)((gg * 16 + wv) * 4 + kc) * 64 + lane];
#pragma unroll
  for (int kc = 0; kc < 8; kc++) {
    whhZ[kc] = (i64)wh8[(long long)((16 + wv) * 8 + kc) * 64 + lane];
    whhN[kc] = (i64)wh8[(long long)((32 + wv) * 8 + kc) * 64 + lane];
  }

  const int col = wv * 16 + cl;
  const float bhh0 = b_hh[col], bhh1 = b_hh[256 + col], bhh2 = b_hh[512 + col];
  const bool vwave = (wv < 7);
  const int vcol = col;
  const bool rowok = (rq < 8);
  const bool vact = vwave && (vcol < V_);
  const bool vld = vact && rowok;
  const float bh = vact ? b_hist[vcol] : 0.f;
  const float cw0 = conv_w[0], cw1 = conv_w[1], cb = conv_b[0];

  const u16* gamp = wsu + WS_GAMMA / 2;
  const u16* x16p = wsu + WS_X16 / 2;
  const u16* xu16p = wsu + WS_XUS16 / 2;
  const u16* xrpp = wsu + WS_XRPRE / 2;
  const u8* m8p = ws8 + WS_M8;
  int lane_p = ((half * 2 + (rq >> 2)) * 16 + cl) & 63;
  const u8* gimp = ws8 + WS_GIM8 + (((long long)cc * 48 + wv) * 64 + lane_p) * 4;

  u32 gaidx = BH_ + (u32)(b0 + rq) * H_ + col;          // gamma[1]
  u32 xidx = (u32)(b0 + rq) * 100 + vcol;
  u32 xuidx = (u32)(b0 + rq) * 99 + vcol;
  u32 midx = (u32)(b0 + rq) * 104 + vcol;
  u32 gidx = (u32)(b0 + rq) * TV_ + vcol;

  float hpr[4] = {0.f, 0.f, 0.f, 0.f};
  float loss_acc = 0.f;
  constexpr float inv128 = 1.f / 128.f;
  constexpr float inv64 = 1.f / 64.f;
  const f32x4 z4 = {0.f, 0.f, 0.f, 0.f};
  const float* xup_dummy = nullptr; (void)xup_dummy;
  __syncthreads();

  for (int t = 0; t < T_; t++) {
    // ---- step-top: issue all global loads ----
    u32 gimw0, gimw1, gimw2;
    {
      const u32* gp = reinterpret_cast<const u32*>(gimp + (long long)t * 393216);
      gimw0 = gp[0]; gimw1 = gp[1024]; gimw2 = gp[2048];
    }
    u16 ga[4] = {0, 0, 0, 0};
    if (rowok) {
#pragma unroll
      for (int j = 0; j < 4; j++) ga[j] = gamp[gaidx + (u32)j * H_];
    }
    gaidx += BH_;
    u16 cx16[4] = {0, 0, 0, 0}, cxu[4] = {0, 0, 0, 0}, cxr[4] = {0, 0, 0, 0};
    u8 cm8[4] = {0, 0, 0, 0};
    if (vld) {
#pragma unroll
      for (int j = 0; j < 4; j++) {
        cx16[j] = x16p[xidx + (u32)j * 100];
        cxu[j]  = xu16p[xuidx + (u32)j * 99];
        cxr[j]  = xrpp[xuidx + (u32)j * 99];
        cm8[j]  = m8p[midx + (u32)j * 104];
      }
    }
    xidx += B_ * 100; xuidx += B_ * 99; midx += B_ * 104;
    const float msv = msum[t];

    // ---- P1: gh chains + x_h ----
    f32x4 accR = z4, accZ = z4, accNh = z4, accXh = z4;
#pragma unroll
    for (int kc = 0; kc < 8; kc++) {
      const i64 a = *reinterpret_cast<const i64*>(&hp8_s[cl * 272 + kc * 32 + kr8]);
      const i64 br = *reinterpret_cast<const i64*>(&whhR_l[(wv * 8 + kc) * 512 + lane * 8]);
      accR  = mfma8(a, br, accR);
      accZ  = mfma8(a, whhZ[kc], accZ);
      accNh = mfma8(a, whhN[kc], accNh);
      if (vwave) {
        const i64 bw = *reinterpret_cast<const i64*>(&whist8_l[(wv * 8 + kc) * 512 + lane * 8]);
        accXh = mfma8(a, bw, accXh);
      }
    }
    if (vld) {
#pragma unroll
      for (int j = 0; j < 4; j++) {
        const float xhv = accXh[j] * inv128 + bh;
        const float ev = cm8[j] ? 0.f : xhv;
        e8_s[(rq + j) * 144 + vcol] = (u8)cvtfp8(ev * 8.f);
      }
    }
    __syncthreads();

    // ---- P2: xr, x_comb, loss, x_imp, xrs ----
    if (vwave) {
      f32x4 acc = z4;
#pragma unroll
      for (int kc = 0; kc < 4; kc++) {
        const i64 a = *reinterpret_cast<const i64*>(&e8_s[cl * 144 + kc * 32 + kr8]);
        const i64 b = *reinterpret_cast<const i64*>(&wr8_l[(wv * 4 + kc) * 512 + lane * 8]);
        acc = mfma8(a, b, acc);
      }
      if (vld) {
        const float inv_ms = 1.f / (msv + 1e-5f);
        float ls = 0.f;
#pragma unroll
        for (int j = 0; j < 4; j++) {
          const float xrv = acc[j] * inv128 + cvt_f32(cxr[j]);
          const float xc = cw0 * cvt_f32(cxu[j]) + cw1 * xrv + cb;
          const float xj = cvt_f32(cx16[j]);
          const bool mj = cm8[j] != 0;
          const float ximp = mj ? xj : xc;
          ls += mj ? fabsf(xj - xc) : 0.f;
          const u32 gj = gidx + (u32)j * TV_;
          out[XIMP_O + gj] = ximp;
          out[XRS_O + gj] = xrv;
          xi8_s[(rq + j) * 144 + vcol] = (u8)cvtfp8(ximp * 8.f);
        }
        loss_acc += ls * inv_ms;
      }
    }
    gidx += V_;
    __syncthreads();

    // ---- P3: gi x-part + GRU update (+ fused gamma[t+1]) ----
    f32x4 accNx = z4;
#pragma unroll
    for (int kc = 0; kc < 4; kc++) {
      const i64 a = *reinterpret_cast<const i64*>(&xi8_s[cl * 144 + kc * 32 + kr8]);
      accR  = mfma8(a, wihx_r[0][kc], accR);
      accZ  = mfma8(a, wihx_r[1][kc], accZ);
      accNx = mfma8(a, wihx_r[2][kc], accNx);
    }
    const f32x4 gimR = dec8x4(gimw0);
    const f32x4 gimZ = dec8x4(gimw1);
    const f32x4 gimN = dec8x4(gimw2);
#pragma unroll
    for (int j = 0; j < 4; j++) {
      const float rr = sigm(accR[j] * inv128 + gimR[j] * inv64 + bhh0);
      const float zz = sigm(accZ[j] * inv128 + gimZ[j] * inv64 + bhh1);
      const float gin = accNx[j] * inv128 + gimN[j] * inv64;
      const float ghn = accNh[j] * inv128 + bhh2;
      const float nn = tanhx(gin + rr * ghn);
      const float hn = (1.f - zz) * nn + zz * hpr[j];
      if (t + 1 < T_) {
        const float hpnew = hn * cvt_f32(ga[j]);
        hpr[j] = hpnew;
        if (rowok) hp8_s[(rq + j) * 272 + col] = (u8)cvtfp8(hpnew * 8.f);
      } else {
        if (rowok) hf_s[rq + j][col] = hn;
      }
    }
    __syncthreads();
  }

  // ---- epilogue ----
  if (tid < 8) {
    float acc = 0.f;
    for (int k = 0; k < H_; k++) acc += hf_s[tid][k] * W_fc[k];
    const float yv = acc + b_fc[0];
    out[YOUT_O + b0 + tid] = yv;
    out[YSC_O + b0 + tid] = 1.f / (1.f + __expf(-yv));
  }
  red_s[tid] = loss_acc;
  __syncthreads();
  for (int s = 512; s; s >>= 1) {
    if (tid < s) red_s[tid] += red_s[tid + s];
    __syncthreads();
  }
  if (tid == 0) {
    float* lp = reinterpret_cast<float*>(reinterpret_cast<char*>(wsu) + WS_LOSSP);
    lp[blockIdx.x] = red_s[0];
  }
}

// ---------------- K3: deterministic loss reduction ----------------
__global__ void k3_loss(const float* __restrict__ lossp, float* __restrict__ out) {
  if (threadIdx.x == 0) {
    float s = 0.f;
    for (int i = 0; i < 64; i++) s += lossp[i];
    out[LOSS_O] = s;
  }
}

extern "C" void kernel_launch(void* const* d_in, const int* in_sizes, int n_in,
                              void* d_out, int out_size, void* d_ws, size_t ws_size,
                              hipStream_t stream) {
  (void)in_sizes; (void)n_in; (void)out_size; (void)ws_size;
  const float* x      = (const float*)d_in[0];
  const float* xhat   = (const float*)d_in[1];
  const float* u      = (const float*)d_in[2];
  const float* m      = (const float*)d_in[3];
  const float* d      = (const float*)d_in[4];
  const float* W_td   = (const float*)d_in[6];
  const float* b_td   = (const float*)d_in[7];
  const float* W_hist = (const float*)d_in[8];
  const float* b_hist = (const float*)d_in[9];
  const float* W_v    = (const float*)d_in[10];
  const float* b_v    = (const float*)d_in[11];
  const float* W_r    = (const float*)d_in[12];
  const float* b_r    = (const float*)d_in[13];
  const float* W_u    = (const float*)d_in[14];
  const float* b_u    = (const float*)d_in[15];
  const float* conv_w = (const float*)d_in[16];
  const float* conv_b = (const float*)d_in[17];
  const float* W_ih   = (const float*)d_in[18];
  const float* b_ih   = (const float*)d_in[19];
  const float* W_hh   = (const float*)d_in[20];
  const float* b_hh   = (const float*)d_in[21];
  const float* W_fc   = (const float*)d_in[22];
  const float* b_fc   = (const float*)d_in[23];
  float* out = (float*)d_out;
  u16* wsu = (u16*)d_ws;
  float* msum = (float*)d_ws;
  const float* lossp = (const float*)((char*)d_ws + WS_LOSSP);

  hipLaunchKernelGGL(k0_pack, dim3(86), dim3(256), 0, stream,
                     W_td, W_u, W_v, W_r, W_ih, msum, wsu);
  hipLaunchKernelGGL(k0b_pack8, dim3(165), dim3(256), 0, stream,
                     W_ih, W_hh, W_hist, W_r, (u8*)d_ws);
  hipLaunchKernelGGL(k2_pre, dim3(1600), dim3(256), 0, stream,
                     x, xhat, u, m, d, b_td, b_u, b_v, b_r, b_ih, msum, out, wsu);
  hipLaunchKernelGGL(k_seq, dim3(64), dim3(1024), 0, stream,
                     b_hist, b_hh, conv_w, conv_b, W_fc, b_fc, msum, out, wsu);
  hipLaunchKernelGGL(k3_loss, dim3(1), dim3(64), 0, stream, lossp, out);
}